// Round 1
// baseline (465.740 us; speedup 1.0000x reference)
//
#include <hip/hip_runtime.h>
#include <math.h>

#define NV   30000
#define DD   256
#define KK   32
#define NCLS 11

// output layout (floats)
#define OZ  0
#define OPB 7680000
#define OLG 7710000
#define OPL 8040000
#define OMB 8070000
#define OMS 8100000
#define OML 8130000
#define OOF 8160000
#define ORG 8190000

typedef __bf16 bf16x8 __attribute__((ext_vector_type(8)));
typedef float  f32x4  __attribute__((ext_vector_type(4)));

__device__ __forceinline__ unsigned short f2b(float f) {
    unsigned u = __float_as_uint(f);
    u += 0x7fffu + ((u >> 16) & 1u);
    return (unsigned short)(u >> 16);
}
__device__ __forceinline__ float gelu_f(float x) {
    return 0.5f * x * (1.0f + erff(x * 0.7071067811865475f));
}

// ---------------- proj = evolved_tokens @ Wp.T + bp ----------------
__global__ void k_proj(const float* __restrict__ et, const float* __restrict__ Wp,
                       const float* __restrict__ bp, float* __restrict__ proj) {
    __shared__ float es[DD];
    int r = blockIdx.x, c = threadIdx.x;
    es[c] = et[r * DD + c];
    __syncthreads();
    const float4* w4 = (const float4*)(Wp + c * DD);
    float acc = bp[c];
#pragma unroll 16
    for (int d = 0; d < DD / 4; ++d) {
        float4 w = w4[d];
        acc += es[4 * d] * w.x + es[4 * d + 1] * w.y + es[4 * d + 2] * w.z + es[4 * d + 3] * w.w;
    }
    proj[r * DD + c] = acc;
}

// ---------------- per-head weight prep: W1e = bf16(W1*ng), W2b = bf16(W2), b1e = b1 + W1@nb ----
__global__ void k_wprep(const float* __restrict__ W1, const float* __restrict__ ng,
                        const float* __restrict__ nb, const float* __restrict__ b1,
                        const float* __restrict__ W2,
                        unsigned short* __restrict__ W1e, unsigned short* __restrict__ W2b,
                        float* __restrict__ b1e) {
    int j = blockIdx.x, d = threadIdx.x;
    float w1 = W1[j * DD + d];
    W1e[j * DD + d] = f2b(w1 * ng[d]);
    W2b[j * DD + d] = f2b(W2[j * DD + d]);
    float p = w1 * nb[d];
#pragma unroll
    for (int m = 1; m < 64; m <<= 1) p += __shfl_xor(p, m);
    __shared__ float red[4];
    if ((d & 63) == 0) red[d >> 6] = p;
    __syncthreads();
    if (d == 0) b1e[j] = b1[j] + red[0] + red[1] + red[2] + red[3];
}

// ---------------- z_out = LN(einsum(aw, proj[vb]) + z0) ----------------
__global__ void k_zout(const float* __restrict__ proj, const int* __restrict__ vb,
                       const float* __restrict__ aw, const float* __restrict__ z0,
                       const float* __restrict__ g, const float* __restrict__ b,
                       float* __restrict__ zout) {
    int n = blockIdx.x, d = threadIdx.x;
    __shared__ float aws[KK];
    __shared__ float red[8];
    if (d < KK) aws[d] = aw[n * KK + d];
    __syncthreads();
    int base = vb[n] * KK * DD;
    float acc = z0[n * DD + d];
#pragma unroll 8
    for (int k = 0; k < KK; ++k) acc += aws[k] * proj[base + k * DD + d];
    float s = acc, q = acc * acc;
#pragma unroll
    for (int m = 1; m < 64; m <<= 1) { s += __shfl_xor(s, m); q += __shfl_xor(q, m); }
    int w = d >> 6;
    if ((d & 63) == 0) { red[w] = s; red[4 + w] = q; }
    __syncthreads();
    s = red[0] + red[1] + red[2] + red[3];
    q = red[4] + red[5] + red[6] + red[7];
    float mean = s * (1.0f / DD);
    float var  = q * (1.0f / DD) - mean * mean;
    float rs   = rsqrtf(var + 1e-5f);
    zout[n * DD + d] = (acc - mean) * rs * g[d] + b[d];
}

// ---------------- masks / offsets / ranges ----------------
__global__ void k_masks(const float* __restrict__ vf, const int* __restrict__ vt,
                        float* __restrict__ out) {
    int n = blockIdx.x * 256 + threadIdx.x;
    if (n >= NV) return;
    float lb = vf[n * 23 + 21], ub = vf[n * 23 + 22];
    int t = vt[n];
    bool is_int = (t == 2);
    bool finite = (fabsf(lb) < 1e18f) && (fabsf(ub) < 1e18f);
    bool small_ = is_int && finite && (ub - lb <= 10.0f);
    bool large_ = is_int && !small_;
    float off = floorf(lb);
    float rngf = ceilf(ub) - off + 1.0f;
    rngf = fminf(fmaxf(rngf, 1.0f), (float)NCLS);
    out[OMB + n] = (t == 1) ? 1.0f : 0.0f;
    out[OMS + n] = small_ ? 1.0f : 0.0f;
    out[OML + n] = large_ ? 1.0f : 0.0f;
    out[OOF + n] = off;
    out[ORG + n] = (float)((int)rngf);
}

// ---------------- fused 3-head MLP kernel ----------------
struct HeadP {
    const unsigned short* W1e;  // bf16, 256x256 row-major (ws)
    const float* b1e;           // ws
    const unsigned short* W2b;  // bf16 (ws)
    const float* b2;
    const float* Wh;            // fp32, nc x 256
    const float* bh;
};

// LDS layout: row-major 64x256 bf16, 16B chunks XOR-swizzled by (row&7)
__device__ __forceinline__ int lidx(int row, int col) {
    return row * 256 + ((((col) >> 3) ^ (row & 7)) << 3) + (col & 7);
}

__device__ __forceinline__ void gemm_tile(const unsigned short* src, const unsigned short* W,
                                          int M0, int wc, int l15, int lq,
                                          f32x4 (&acc)[2][8]) {
    int kq = lq * 8;
    int r0 = M0 + l15;
    int sw = (r0 & 7);
#pragma unroll 2
    for (int k0 = 0; k0 < 256; k0 += 32) {
        int ch = (k0 >> 3) + lq;
        bf16x8 a0 = *(const bf16x8*)(src + r0 * 256 + ((ch ^ sw) << 3));
        bf16x8 a1 = *(const bf16x8*)(src + (r0 + 16) * 256 + ((ch ^ sw) << 3));
        const unsigned short* wb = W + (wc * 128 + l15) * 256 + k0 + kq;
#pragma unroll
        for (int t = 0; t < 8; ++t) {
            bf16x8 b = *(const bf16x8*)(wb + t * 16 * 256);
            acc[0][t] = __builtin_amdgcn_mfma_f32_16x16x32_bf16(a0, b, acc[0][t], 0, 0, 0);
            acc[1][t] = __builtin_amdgcn_mfma_f32_16x16x32_bf16(a1, b, acc[1][t], 0, 0, 0);
        }
    }
}

__global__ __launch_bounds__(256, 2)
void k_heads(const float* __restrict__ zout, const float* __restrict__ ranges,
             HeadP h0, HeadP h1p, HeadP h2p,
             float* __restrict__ opb, float* __restrict__ olg, float* __restrict__ opl) {
    __shared__ unsigned short zl[64 * 256];
    __shared__ unsigned short hl[64 * 256];
    int n0 = blockIdx.x * 64;
    int tid = threadIdx.x;

    // ---- zhat = rownorm(z_out) -> zl (bf16, swizzled) ----
    {
        int row = tid >> 2, qq = tid & 3;
        int n = n0 + row;
        bool ok = n < NV;
        const float4* zp = (const float4*)(zout + (size_t)n * DD + qq * 64);
        float s = 0.f, q = 0.f;
        float4 v[16];
#pragma unroll
        for (int i = 0; i < 16; ++i) {
            v[i] = ok ? zp[i] : make_float4(0.f, 0.f, 0.f, 0.f);
            s += v[i].x + v[i].y + v[i].z + v[i].w;
            q += v[i].x * v[i].x + v[i].y * v[i].y + v[i].z * v[i].z + v[i].w * v[i].w;
        }
        s += __shfl_xor(s, 1); s += __shfl_xor(s, 2);
        q += __shfl_xor(q, 1); q += __shfl_xor(q, 2);
        float mean = s * (1.f / 256.f);
        float var  = q * (1.f / 256.f) - mean * mean;
        float rs   = rsqrtf(var + 1e-5f);
        int sw = row & 7;
#pragma unroll
        for (int i = 0; i < 8; ++i) {
            int chunk = qq * 8 + i;
            int phys = row * 256 + ((chunk ^ sw) << 3);
            float4 a = v[2 * i], b4 = v[2 * i + 1];
            unsigned u0 = (unsigned)f2b((a.x - mean) * rs) | ((unsigned)f2b((a.y - mean) * rs) << 16);
            unsigned u1 = (unsigned)f2b((a.z - mean) * rs) | ((unsigned)f2b((a.w - mean) * rs) << 16);
            unsigned u2 = (unsigned)f2b((b4.x - mean) * rs) | ((unsigned)f2b((b4.y - mean) * rs) << 16);
            unsigned u3 = (unsigned)f2b((b4.z - mean) * rs) | ((unsigned)f2b((b4.w - mean) * rs) << 16);
            *((uint4*)&zl[phys]) = make_uint4(u0, u1, u2, u3);
        }
    }
    __syncthreads();

    int lane = tid & 63, wv = tid >> 6;
    int wr = wv >> 1, wc = wv & 1;
    int l15 = lane & 15, lq = lane >> 4;
    int M0 = wr * 32;
    float* pb = (float*)hl;  // partial buffer view: row stride 128 floats

    for (int head = 0; head < 3; ++head) {
        HeadP hp = (head == 0) ? h0 : ((head == 1) ? h1p : h2p);
        int nc = (head == 1) ? NCLS : 1;

        f32x4 acc[2][8];
#pragma unroll
        for (int i = 0; i < 2; ++i)
#pragma unroll
            for (int t = 0; t < 8; ++t) acc[i][t] = f32x4{0.f, 0.f, 0.f, 0.f};

        // GEMM1: zhat @ W1e.T
        gemm_tile(zl, hp.W1e, M0, wc, l15, lq, acc);

        // epilogue 1: +b1e, gelu, -> hl (bf16)
#pragma unroll
        for (int t = 0; t < 8; ++t) {
            int col = wc * 128 + 16 * t + l15;
            float bias = hp.b1e[col];
#pragma unroll
            for (int i = 0; i < 2; ++i) {
#pragma unroll
                for (int r = 0; r < 4; ++r) {
                    int row = M0 + 16 * i + lq * 4 + r;
                    hl[lidx(row, col)] = f2b(gelu_f(acc[i][t][r] + bias));
                }
            }
        }
        __syncthreads();

        // GEMM2: h1 @ W2.T
#pragma unroll
        for (int i = 0; i < 2; ++i)
#pragma unroll
            for (int t = 0; t < 8; ++t) acc[i][t] = f32x4{0.f, 0.f, 0.f, 0.f};
        gemm_tile(hl, hp.W2b, M0, wc, l15, lq, acc);

        // epilogue 2: +b2, gelu, + residual z_out  -> R (kept in acc)
#pragma unroll
        for (int t = 0; t < 8; ++t) {
            int col = wc * 128 + 16 * t + l15;
            float bias = hp.b2[col];
#pragma unroll
            for (int i = 0; i < 2; ++i) {
#pragma unroll
                for (int r = 0; r < 4; ++r) {
                    int row = M0 + 16 * i + lq * 4 + r;
                    int n = n0 + row;
                    float z = (n < NV) ? zout[(size_t)n * DD + col] : 0.f;
                    acc[i][t][r] = gelu_f(acc[i][t][r] + bias) + z;
                }
            }
        }
        __syncthreads();  // everyone done reading hl before partials overwrite it

        // head projection: partial dots over this wave's column half
        for (int o = 0; o < nc; ++o) {
#pragma unroll
            for (int i = 0; i < 2; ++i) {
                float p0 = 0.f, p1 = 0.f, p2 = 0.f, p3 = 0.f;
#pragma unroll
                for (int t = 0; t < 8; ++t) {
                    float wv_ = hp.Wh[o * DD + wc * 128 + 16 * t + l15];
                    p0 += acc[i][t][0] * wv_; p1 += acc[i][t][1] * wv_;
                    p2 += acc[i][t][2] * wv_; p3 += acc[i][t][3] * wv_;
                }
#pragma unroll
                for (int m = 1; m < 16; m <<= 1) {
                    p0 += __shfl_xor(p0, m); p1 += __shfl_xor(p1, m);
                    p2 += __shfl_xor(p2, m); p3 += __shfl_xor(p3, m);
                }
                if (l15 == 0) {
                    int rb = M0 + 16 * i + lq * 4;
                    pb[(rb + 0) * 128 + 2 * o + wc] = p0;
                    pb[(rb + 1) * 128 + 2 * o + wc] = p1;
                    pb[(rb + 2) * 128 + 2 * o + wc] = p2;
                    pb[(rb + 3) * 128 + 2 * o + wc] = p3;
                }
            }
        }
        __syncthreads();

        // combine halves + bias + activation/mask + store
        for (int idx = tid; idx < 64 * nc; idx += 256) {
            int row, o;
            if (nc == 1) { row = idx; o = 0; }
            else { row = idx / NCLS; o = idx - row * NCLS; }
            int n = n0 + row;
            if (n < NV) {
                float val = pb[row * 128 + 2 * o] + pb[row * 128 + 2 * o + 1] + hp.bh[o];
                if (head == 0)      opb[n] = 1.f / (1.f + expf(-val));
                else if (head == 2) opl[n] = val;
                else {
                    int rng = (int)ranges[n];
                    olg[n * NCLS + o] = (o < rng) ? val : -1e9f;
                }
            }
        }
        __syncthreads();
    }
}

extern "C" void kernel_launch(void* const* d_in, const int* in_sizes, int n_in,
                              void* d_out, int out_size, void* d_ws, size_t ws_size,
                              hipStream_t stream) {
    const float* et = (const float*)d_in[0];
    const int*   vb = (const int*)d_in[1];
    const float* aw = (const float*)d_in[2];
    const int*   vt = (const int*)d_in[3];
    const float* z0 = (const float*)d_in[4];
    const float* vf = (const float*)d_in[5];
    const float* Wp = (const float*)d_in[6];
    const float* bp = (const float*)d_in[7];
    const float* fg = (const float*)d_in[8];
    const float* fb = (const float*)d_in[9];
    float* out = (float*)d_out;

    char* ws = (char*)d_ws;
    float* proj          = (float*)ws;                   // 262144 B
    float* b1e           = (float*)(ws + 262144);        // 3072 B
    unsigned short* W1e  = (unsigned short*)(ws + 265216);  // 393216 B
    unsigned short* W2b  = (unsigned short*)(ws + 658432);  // 393216 B

    k_proj<<<256, 256, 0, stream>>>(et, Wp, bp, proj);
    for (int h = 0; h < 3; ++h) {
        k_wprep<<<256, 256, 0, stream>>>(
            (const float*)d_in[12 + 8 * h], (const float*)d_in[10 + 8 * h],
            (const float*)d_in[11 + 8 * h], (const float*)d_in[13 + 8 * h],
            (const float*)d_in[14 + 8 * h],
            W1e + h * 65536, W2b + h * 65536, b1e + h * 256);
    }
    k_zout<<<NV, 256, 0, stream>>>(proj, vb, aw, z0, fg, fb, out + OZ);
    k_masks<<<(NV + 255) / 256, 256, 0, stream>>>(vf, vt, out);

    HeadP hps[3];
    for (int h = 0; h < 3; ++h) {
        hps[h].W1e = W1e + h * 65536;
        hps[h].b1e = b1e + h * 256;
        hps[h].W2b = W2b + h * 65536;
        hps[h].b2  = (const float*)d_in[15 + 8 * h];
        hps[h].Wh  = (const float*)d_in[16 + 8 * h];
        hps[h].bh  = (const float*)d_in[17 + 8 * h];
    }
    k_heads<<<(NV + 63) / 64, 256, 0, stream>>>(out + OZ, out + ORG,
                                                hps[0], hps[1], hps[2],
                                                out + OPB, out + OLG, out + OPL);
}

// Round 2
// 348.122 us; speedup vs baseline: 1.3379x; 1.3379x over previous
//
#include <hip/hip_runtime.h>
#include <math.h>

#define NV   30000
#define DD   256
#define KK   32
#define NCLS 11
#define NT   469   // row tiles of 64

// output layout (floats)
#define OZ  0
#define OPB 7680000
#define OLG 7710000
#define OPL 8040000
#define OMB 8070000
#define OMS 8100000
#define OML 8130000
#define OOF 8160000
#define ORG 8190000

typedef __bf16 bf16x8 __attribute__((ext_vector_type(8)));
typedef float  f32x4  __attribute__((ext_vector_type(4)));

__device__ __forceinline__ unsigned short f2b(float f) {
    unsigned u = __float_as_uint(f);
    u += 0x7fffu + ((u >> 16) & 1u);
    return (unsigned short)(u >> 16);
}
__device__ __forceinline__ float gelu_f(float x) {
    return 0.5f * x * (1.0f + erff(x * 0.7071067811865475f));
}

// ---------------- proj = evolved_tokens @ Wp.T + bp ----------------
__global__ void k_proj(const float* __restrict__ et, const float* __restrict__ Wp,
                       const float* __restrict__ bp, float* __restrict__ proj) {
    __shared__ float es[DD];
    int r = blockIdx.x, c = threadIdx.x;
    es[c] = et[r * DD + c];
    __syncthreads();
    const float4* w4 = (const float4*)(Wp + c * DD);
    float acc = bp[c];
#pragma unroll 16
    for (int d = 0; d < DD / 4; ++d) {
        float4 w = w4[d];
        acc += es[4 * d] * w.x + es[4 * d + 1] * w.y + es[4 * d + 2] * w.z + es[4 * d + 3] * w.w;
    }
    proj[r * DD + c] = acc;
}

// ---------------- per-head weight prep ----------------
__global__ void k_wprep(const float* __restrict__ W1, const float* __restrict__ ng,
                        const float* __restrict__ nb, const float* __restrict__ b1,
                        const float* __restrict__ W2,
                        unsigned short* __restrict__ W1e, unsigned short* __restrict__ W2b,
                        float* __restrict__ b1e) {
    int j = blockIdx.x, d = threadIdx.x;
    float w1 = W1[j * DD + d];
    W1e[j * DD + d] = f2b(w1 * ng[d]);
    W2b[j * DD + d] = f2b(W2[j * DD + d]);
    float p = w1 * nb[d];
#pragma unroll
    for (int m = 1; m < 64; m <<= 1) p += __shfl_xor(p, m);
    __shared__ float red[4];
    if ((d & 63) == 0) red[d >> 6] = p;
    __syncthreads();
    if (d == 0) b1e[j] = b1[j] + red[0] + red[1] + red[2] + red[3];
}

// ---- z_out = LN(einsum+z0); also zhat=rownorm(z_out) bf16; zwh[n][o]=z_out·Wh_o ----
__global__ __launch_bounds__(256)
void k_zout(const float* __restrict__ proj, const int* __restrict__ vb,
            const float* __restrict__ aw, const float* __restrict__ z0,
            const float* __restrict__ g, const float* __restrict__ b,
            const float* __restrict__ Wh0, const float* __restrict__ Wh1,
            const float* __restrict__ Wh2,
            float* __restrict__ zout, unsigned short* __restrict__ zhat,
            float* __restrict__ zwh) {
    int wv = threadIdx.x >> 6, lane = threadIdx.x & 63;
    int n = blockIdx.x * 4 + wv;
    if (n >= NV) return;
    int bidx = vb[n];
    float awv = aw[n * KK + (lane & 31)];
    const float4* pr = (const float4*)(proj + (size_t)bidx * KK * DD);
    float4 acc = ((const float4*)(z0 + (size_t)n * DD))[lane];
#pragma unroll 8
    for (int k = 0; k < KK; ++k) {
        float a = __shfl(awv, k);
        float4 p = pr[k * 64 + lane];
        acc.x += a * p.x; acc.y += a * p.y; acc.z += a * p.z; acc.w += a * p.w;
    }
    // LN1
    float s = acc.x + acc.y + acc.z + acc.w;
    float q = acc.x * acc.x + acc.y * acc.y + acc.z * acc.z + acc.w * acc.w;
#pragma unroll
    for (int m = 1; m < 64; m <<= 1) { s += __shfl_xor(s, m); q += __shfl_xor(q, m); }
    float mean = s * (1.f / DD);
    float var  = q * (1.f / DD) - mean * mean;
    float rs   = rsqrtf(var + 1e-5f);
    float4 g4 = ((const float4*)g)[lane], b4 = ((const float4*)b)[lane];
    float4 z;
    z.x = (acc.x - mean) * rs * g4.x + b4.x;
    z.y = (acc.y - mean) * rs * g4.y + b4.y;
    z.z = (acc.z - mean) * rs * g4.z + b4.z;
    z.w = (acc.w - mean) * rs * g4.w + b4.w;
    ((float4*)(zout + (size_t)n * DD))[lane] = z;
    // LN2 (no affine) -> zhat bf16
    float s2 = z.x + z.y + z.z + z.w;
    float q2 = z.x * z.x + z.y * z.y + z.z * z.z + z.w * z.w;
#pragma unroll
    for (int m = 1; m < 64; m <<= 1) { s2 += __shfl_xor(s2, m); q2 += __shfl_xor(q2, m); }
    float m2 = s2 * (1.f / DD);
    float v2 = q2 * (1.f / DD) - m2 * m2;
    float r2 = rsqrtf(v2 + 1e-5f);
    ushort4 zh;
    zh.x = f2b((z.x - m2) * r2); zh.y = f2b((z.y - m2) * r2);
    zh.z = f2b((z.z - m2) * r2); zh.w = f2b((z.w - m2) * r2);
    *(ushort4*)(zhat + (size_t)n * DD + 4 * lane) = zh;
    // z.Wh dots for all 13 head outputs
    const float* whp[3] = {Wh0, Wh1, Wh2};
    int ncs[3] = {1, NCLS, 1};
    int ob = 0;
    for (int h = 0; h < 3; ++h) {
        for (int o = 0; o < ncs[h]; ++o) {
            float4 w = ((const float4*)(whp[h] + o * DD))[lane];
            float p = z.x * w.x + z.y * w.y + z.z * w.z + z.w * w.w;
#pragma unroll
            for (int m = 1; m < 64; m <<= 1) p += __shfl_xor(p, m);
            if (lane == 0) zwh[(size_t)n * 16 + ob + o] = p;
        }
        ob += ncs[h];
    }
}

// ---------------- masks / offsets / ranges ----------------
__global__ void k_masks(const float* __restrict__ vf, const int* __restrict__ vt,
                        float* __restrict__ out) {
    int n = blockIdx.x * 256 + threadIdx.x;
    if (n >= NV) return;
    float lb = vf[n * 23 + 21], ub = vf[n * 23 + 22];
    int t = vt[n];
    bool is_int = (t == 2);
    bool finite = (fabsf(lb) < 1e18f) && (fabsf(ub) < 1e18f);
    bool small_ = is_int && finite && (ub - lb <= 10.0f);
    bool large_ = is_int && !small_;
    float off = floorf(lb);
    float rngf = ceilf(ub) - off + 1.0f;
    rngf = fminf(fmaxf(rngf, 1.0f), (float)NCLS);
    out[OMB + n] = (t == 1) ? 1.0f : 0.0f;
    out[OMS + n] = small_ ? 1.0f : 0.0f;
    out[OML + n] = large_ ? 1.0f : 0.0f;
    out[OOF + n] = off;
    out[ORG + n] = (float)((int)rngf);
}

// ---------------- per-head MLP kernel (one head per block) ----------------
struct HeadP {
    const unsigned short* W1e;
    const float* b1e;
    const unsigned short* W2b;
    const float* b2;
    const float* Wh;
    const float* bh;
    int nc;
    int obase;
};

__device__ __forceinline__ int lidx(int row, int col) {
    return row * 256 + ((((col) >> 3) ^ (row & 7)) << 3) + (col & 7);
}

// A from global (row-major bf16, 256-wide), B = weight (row-major bf16 256x256)
__device__ __forceinline__ void gemm_g(const unsigned short* A0, const unsigned short* W,
                                       f32x4 (&acc)[2][8]) {
#pragma unroll 2
    for (int k0 = 0; k0 < 256; k0 += 32) {
        bf16x8 a0 = *(const bf16x8*)(A0 + k0);
        bf16x8 a1 = *(const bf16x8*)(A0 + 16 * 256 + k0);
#pragma unroll
        for (int t = 0; t < 8; ++t) {
            bf16x8 b = *(const bf16x8*)(W + k0 + t * 16 * 256);
            acc[0][t] = __builtin_amdgcn_mfma_f32_16x16x32_bf16(a0, b, acc[0][t], 0, 0, 0);
            acc[1][t] = __builtin_amdgcn_mfma_f32_16x16x32_bf16(a1, b, acc[1][t], 0, 0, 0);
        }
    }
}

// A from LDS (swizzled 64x256 bf16), B = weight global
__device__ __forceinline__ void gemm_l(const unsigned short* src, const unsigned short* W,
                                       int M0, int l15, int lq, f32x4 (&acc)[2][8]) {
    int r0 = M0 + l15;
    int sw = (r0 & 7);
#pragma unroll 2
    for (int k0 = 0; k0 < 256; k0 += 32) {
        int ch = (k0 >> 3) + lq;
        bf16x8 a0 = *(const bf16x8*)(src + r0 * 256 + ((ch ^ sw) << 3));
        bf16x8 a1 = *(const bf16x8*)(src + (r0 + 16) * 256 + ((ch ^ sw) << 3));
#pragma unroll
        for (int t = 0; t < 8; ++t) {
            bf16x8 b = *(const bf16x8*)(W + k0 + t * 16 * 256);
            acc[0][t] = __builtin_amdgcn_mfma_f32_16x16x32_bf16(a0, b, acc[0][t], 0, 0, 0);
            acc[1][t] = __builtin_amdgcn_mfma_f32_16x16x32_bf16(a1, b, acc[1][t], 0, 0, 0);
        }
    }
}

__global__ __launch_bounds__(256, 3)
void k_heads(const unsigned short* __restrict__ zhat, const float* __restrict__ zwh,
             const float* __restrict__ ranges,
             HeadP h0, HeadP h1p, HeadP h2p,
             float* __restrict__ opb, float* __restrict__ olg, float* __restrict__ opl) {
    __shared__ unsigned short hl[64 * 256];   // 32 KB (reused as partials)
    __shared__ float whs[NCLS * 256];         // 11 KB
    __shared__ float b1s[DD], b2s[DD];
    __shared__ float zws[64 * NCLS];
    __shared__ float bhs[NCLS];

    int head = blockIdx.x / NT;
    int tile = blockIdx.x % NT;
    HeadP hp = (head == 0) ? h0 : ((head == 1) ? h1p : h2p);
    int nc = hp.nc;
    int n0 = tile * 64;
    int tid = threadIdx.x;

    // stage weights/biases/zwh into LDS
    for (int i = tid; i < nc * DD; i += 256) whs[i] = hp.Wh[i];
    b1s[tid] = hp.b1e[tid];
    b2s[tid] = hp.b2[tid];
    for (int i = tid; i < 64 * nc; i += 256) {
        int r = i / nc, o = i - r * nc;
        int n = n0 + r;
        zws[i] = (n < NV) ? zwh[(size_t)n * 16 + hp.obase + o] : 0.f;
    }
    if (tid < nc) bhs[tid] = hp.bh[tid];
    __syncthreads();

    int lane = tid & 63, wv = tid >> 6;
    int wr = wv >> 1, wc = wv & 1;
    int l15 = lane & 15, lq = lane >> 4;
    int M0 = wr * 32;
    float* pb = (float*)hl;

    f32x4 acc[2][8];
#pragma unroll
    for (int i = 0; i < 2; ++i)
#pragma unroll
        for (int t = 0; t < 8; ++t) acc[i][t] = f32x4{0.f, 0.f, 0.f, 0.f};

    // GEMM1: zhat @ W1e.T  (A straight from global)
    const unsigned short* A0 = zhat + (size_t)(n0 + M0 + l15) * DD + lq * 8;
    const unsigned short* Wb1 = hp.W1e + (wc * 128 + l15) * DD + lq * 8;
    gemm_g(A0, Wb1, acc);

    // epilogue 1: +b1e, gelu -> hl (bf16, swizzled)
#pragma unroll
    for (int t = 0; t < 8; ++t) {
        int col = wc * 128 + 16 * t + l15;
        float bias = b1s[col];
#pragma unroll
        for (int i = 0; i < 2; ++i) {
#pragma unroll
            for (int r = 0; r < 4; ++r) {
                int row = M0 + 16 * i + lq * 4 + r;
                hl[lidx(row, col)] = f2b(gelu_f(acc[i][t][r] + bias));
            }
        }
    }
    __syncthreads();

    // GEMM2: h1 @ W2.T
#pragma unroll
    for (int i = 0; i < 2; ++i)
#pragma unroll
        for (int t = 0; t < 8; ++t) acc[i][t] = f32x4{0.f, 0.f, 0.f, 0.f};
    const unsigned short* Wb2 = hp.W2b + (wc * 128 + l15) * DD + lq * 8;
    gemm_l(hl, Wb2, M0, l15, lq, acc);

    // epilogue 2: h = gelu(acc + b2)  (residual folded into zws)
#pragma unroll
    for (int t = 0; t < 8; ++t) {
        int col = wc * 128 + 16 * t + l15;
        float bias = b2s[col];
#pragma unroll
        for (int i = 0; i < 2; ++i) {
#pragma unroll
            for (int r = 0; r < 4; ++r) {
                acc[i][t][r] = gelu_f(acc[i][t][r] + bias);
            }
        }
    }
    __syncthreads();  // hl free now

    // head projection: partial dots over this wave's column half (Wh from LDS)
    for (int o = 0; o < nc; ++o) {
#pragma unroll
        for (int i = 0; i < 2; ++i) {
            float p0 = 0.f, p1 = 0.f, p2 = 0.f, p3 = 0.f;
#pragma unroll
            for (int t = 0; t < 8; ++t) {
                float w = whs[o * DD + wc * 128 + 16 * t + l15];
                p0 += acc[i][t][0] * w; p1 += acc[i][t][1] * w;
                p2 += acc[i][t][2] * w; p3 += acc[i][t][3] * w;
            }
#pragma unroll
            for (int m = 1; m < 16; m <<= 1) {
                p0 += __shfl_xor(p0, m); p1 += __shfl_xor(p1, m);
                p2 += __shfl_xor(p2, m); p3 += __shfl_xor(p3, m);
            }
            if (l15 == 0) {
                int rb = M0 + 16 * i + lq * 4;
                pb[(rb + 0) * 128 + 2 * o + wc] = p0;
                pb[(rb + 1) * 128 + 2 * o + wc] = p1;
                pb[(rb + 2) * 128 + 2 * o + wc] = p2;
                pb[(rb + 3) * 128 + 2 * o + wc] = p3;
            }
        }
    }
    __syncthreads();

    // combine halves + zwh + bh + activation/mask + store
    for (int idx = tid; idx < 64 * nc; idx += 256) {
        int row, o;
        if (nc == 1) { row = idx; o = 0; }
        else { row = idx / NCLS; o = idx - row * NCLS; }
        int n = n0 + row;
        if (n < NV) {
            float val = pb[row * 128 + 2 * o] + pb[row * 128 + 2 * o + 1]
                      + zws[row * nc + o] + bhs[o];
            if (head == 0)      opb[n] = 1.f / (1.f + expf(-val));
            else if (head == 2) opl[n] = val;
            else {
                int rng = (int)ranges[n];
                olg[n * NCLS + o] = (o < rng) ? val : -1e9f;
            }
        }
    }
}

extern "C" void kernel_launch(void* const* d_in, const int* in_sizes, int n_in,
                              void* d_out, int out_size, void* d_ws, size_t ws_size,
                              hipStream_t stream) {
    const float* et = (const float*)d_in[0];
    const int*   vb = (const int*)d_in[1];
    const float* aw = (const float*)d_in[2];
    const int*   vt = (const int*)d_in[3];
    const float* z0 = (const float*)d_in[4];
    const float* vf = (const float*)d_in[5];
    const float* Wp = (const float*)d_in[6];
    const float* bp = (const float*)d_in[7];
    const float* fg = (const float*)d_in[8];
    const float* fb = (const float*)d_in[9];
    float* out = (float*)d_out;

    char* ws = (char*)d_ws;
    float* proj          = (float*)ws;                        // 262144 B
    float* b1e           = (float*)(ws + 262144);             // 3072 B (+pad)
    unsigned short* W1e  = (unsigned short*)(ws + 265216);    // 393216 B
    unsigned short* W2b  = (unsigned short*)(ws + 658432);    // 393216 B
    unsigned short* zhat = (unsigned short*)(ws + 1051648);   // 30016*512 B
    float* zwh           = (float*)(ws + 16419840);           // 30016*64 B -> end 18340864

    k_proj<<<256, 256, 0, stream>>>(et, Wp, bp, proj);
    for (int h = 0; h < 3; ++h) {
        k_wprep<<<256, 256, 0, stream>>>(
            (const float*)d_in[12 + 8 * h], (const float*)d_in[10 + 8 * h],
            (const float*)d_in[11 + 8 * h], (const float*)d_in[13 + 8 * h],
            (const float*)d_in[14 + 8 * h],
            W1e + h * 65536, W2b + h * 65536, b1e + h * 256);
    }
    k_zout<<<7500, 256, 0, stream>>>(proj, vb, aw, z0, fg, fb,
                                     (const float*)d_in[16], (const float*)d_in[24],
                                     (const float*)d_in[32],
                                     out + OZ, zhat, zwh);
    k_masks<<<(NV + 255) / 256, 256, 0, stream>>>(vf, vt, out);

    HeadP hps[3];
    int obase[3] = {0, 1, 12};
    for (int h = 0; h < 3; ++h) {
        hps[h].W1e = W1e + h * 65536;
        hps[h].b1e = b1e + h * 256;
        hps[h].W2b = W2b + h * 65536;
        hps[h].b2  = (const float*)d_in[15 + 8 * h];
        hps[h].Wh  = (const float*)d_in[16 + 8 * h];
        hps[h].bh  = (const float*)d_in[17 + 8 * h];
        hps[h].nc  = (h == 1) ? NCLS : 1;
        hps[h].obase = obase[h];
    }
    k_heads<<<3 * NT, 256, 0, stream>>>(zhat, zwh, out + ORG,
                                        hps[0], hps[1], hps[2],
                                        out + OPB, out + OLG, out + OPL);
}

// Round 4
// 322.271 us; speedup vs baseline: 1.4452x; 1.0802x over previous
//
#include <hip/hip_runtime.h>
#include <math.h>

#define NV   30000
#define DD   256
#define KK   32
#define NCLS 11
#define NT   469   // row tiles of 64

// output layout (floats)
#define OZ  0
#define OPB 7680000
#define OLG 7710000
#define OPL 8040000
#define OMB 8070000
#define OMS 8100000
#define OML 8130000
#define OOF 8160000
#define ORG 8190000

typedef __bf16 bf16x8 __attribute__((ext_vector_type(8)));
typedef float  f32x4  __attribute__((ext_vector_type(4)));

__device__ __forceinline__ unsigned short f2b(float f) {
    unsigned u = __float_as_uint(f);
    u += 0x7fffu + ((u >> 16) & 1u);
    return (unsigned short)(u >> 16);
}

// gelu via A&S 7.1.26 erf approx (|eps|<=1.5e-7), ~12 VALU ops vs ~30 for libm erff
__device__ __forceinline__ float gelu_f(float x) {
    float y = fabsf(x) * 0.70710678118f;
    float t = __builtin_amdgcn_rcpf(__builtin_fmaf(0.3275911f, y, 1.0f));
    float p = t * (0.254829592f + t * (-0.284496736f + t * (1.421413741f +
              t * (-1.453152027f + t * 1.061405429f))));
    float e = __expf(-y * y);
    float erfa = __builtin_fmaf(-p, e, 1.0f);
    float erfv = copysignf(erfa, x);
    return 0.5f * x * (1.0f + erfv);
}

// swizzle: include row>>3 so 4-row-apart quads land on distinct 16B groups
__device__ __forceinline__ int swz(int row) { return (row + (row >> 3)) & 7; }
__device__ __forceinline__ int lidx(int row, int col) {
    return row * 256 + ((((col) >> 3) ^ swz(row)) << 3) + (col & 7);
}

// ---------------- proj = evolved_tokens @ Wp.T + bp ----------------
__global__ void k_proj(const float* __restrict__ et, const float* __restrict__ Wp,
                       const float* __restrict__ bp, float* __restrict__ proj) {
    __shared__ float es[DD];
    int r = blockIdx.x, c = threadIdx.x;
    es[c] = et[r * DD + c];
    __syncthreads();
    const float4* w4 = (const float4*)(Wp + c * DD);
    float acc = bp[c];
#pragma unroll 16
    for (int d = 0; d < DD / 4; ++d) {
        float4 w = w4[d];
        acc += es[4 * d] * w.x + es[4 * d + 1] * w.y + es[4 * d + 2] * w.z + es[4 * d + 3] * w.w;
    }
    proj[r * DD + c] = acc;
}

// ---------------- merged weight prep (3 heads via blockIdx.y) ----------------
struct WP {
    const float *W1, *ng, *nb, *b1, *W2;
    unsigned short *W1e, *W2b;
    float *b1e;
};

__global__ void k_wprep(WP wa, WP wb, WP wc) {
    WP wp = (blockIdx.y == 0) ? wa : ((blockIdx.y == 1) ? wb : wc);
    int j = blockIdx.x, d = threadIdx.x;
    float v1 = wp.W1[j * DD + d];
    wp.W1e[j * DD + d] = f2b(v1 * wp.ng[d]);
    wp.W2b[j * DD + d] = f2b(wp.W2[j * DD + d]);
    float p = v1 * wp.nb[d];
#pragma unroll
    for (int m = 1; m < 64; m <<= 1) p += __shfl_xor(p, m);
    __shared__ float red[4];
    if ((d & 63) == 0) red[d >> 6] = p;
    __syncthreads();
    if (d == 0) wp.b1e[j] = wp.b1[j] + red[0] + red[1] + red[2] + red[3];
}

// ---- z_out = LN(einsum+z0); zhat bf16; zwh dots; masks fused ----
__global__ __launch_bounds__(256)
void k_zout(const float* __restrict__ proj, const int* __restrict__ vb,
            const float* __restrict__ aw, const float* __restrict__ z0,
            const float* __restrict__ g, const float* __restrict__ b,
            const float* __restrict__ Wh0, const float* __restrict__ Wh1,
            const float* __restrict__ Wh2,
            const float* __restrict__ vf, const int* __restrict__ vt,
            float* __restrict__ out, unsigned short* __restrict__ zhat,
            float* __restrict__ zwh) {
    int wv = threadIdx.x >> 6, lane = threadIdx.x & 63;
    int n = blockIdx.x * 4 + wv;
    if (n >= NV) return;
    int bidx = vb[n];
    float awv = aw[n * KK + (lane & 31)];
    const float4* pr = (const float4*)(proj + (size_t)bidx * KK * DD);
    float4 acc = ((const float4*)(z0 + (size_t)n * DD))[lane];
#pragma unroll 8
    for (int k = 0; k < KK; ++k) {
        float a = __shfl(awv, k);
        float4 p = pr[k * 64 + lane];
        acc.x += a * p.x; acc.y += a * p.y; acc.z += a * p.z; acc.w += a * p.w;
    }
    // LN1
    float s = acc.x + acc.y + acc.z + acc.w;
    float q = acc.x * acc.x + acc.y * acc.y + acc.z * acc.z + acc.w * acc.w;
#pragma unroll
    for (int m = 1; m < 64; m <<= 1) { s += __shfl_xor(s, m); q += __shfl_xor(q, m); }
    float mean = s * (1.f / DD);
    float var  = q * (1.f / DD) - mean * mean;
    float rs   = rsqrtf(var + 1e-5f);
    float4 g4 = ((const float4*)g)[lane], b4 = ((const float4*)b)[lane];
    float4 z;
    z.x = (acc.x - mean) * rs * g4.x + b4.x;
    z.y = (acc.y - mean) * rs * g4.y + b4.y;
    z.z = (acc.z - mean) * rs * g4.z + b4.z;
    z.w = (acc.w - mean) * rs * g4.w + b4.w;
    ((float4*)(out + OZ + (size_t)n * DD))[lane] = z;
    // LN2 (no affine) -> zhat bf16
    float s2 = z.x + z.y + z.z + z.w;
    float q2 = z.x * z.x + z.y * z.y + z.z * z.z + z.w * z.w;
#pragma unroll
    for (int m = 1; m < 64; m <<= 1) { s2 += __shfl_xor(s2, m); q2 += __shfl_xor(q2, m); }
    float m2 = s2 * (1.f / DD);
    float v2 = q2 * (1.f / DD) - m2 * m2;
    float r2 = rsqrtf(v2 + 1e-5f);
    ushort4 zh;
    zh.x = f2b((z.x - m2) * r2); zh.y = f2b((z.y - m2) * r2);
    zh.z = f2b((z.z - m2) * r2); zh.w = f2b((z.w - m2) * r2);
    *(ushort4*)(zhat + (size_t)n * DD + 4 * lane) = zh;
    // z.Wh dots for all 13 head outputs
    const float* whp[3] = {Wh0, Wh1, Wh2};
    int ncs[3] = {1, NCLS, 1};
    int ob = 0;
    for (int h = 0; h < 3; ++h) {
        for (int o = 0; o < ncs[h]; ++o) {
            float4 w = ((const float4*)(whp[h] + o * DD))[lane];
            float p = z.x * w.x + z.y * w.y + z.z * w.z + z.w * w.w;
#pragma unroll
            for (int m = 1; m < 64; m <<= 1) p += __shfl_xor(p, m);
            if (lane == 0) zwh[(size_t)n * 16 + ob + o] = p;
        }
        ob += ncs[h];
    }
    // fused masks/offsets/ranges (lane 0)
    if (lane == 0) {
        float lb = vf[n * 23 + 21], ub = vf[n * 23 + 22];
        int t = vt[n];
        bool is_int = (t == 2);
        bool finite = (fabsf(lb) < 1e18f) && (fabsf(ub) < 1e18f);
        bool small_ = is_int && finite && (ub - lb <= 10.0f);
        float off = floorf(lb);
        float rngf = ceilf(ub) - off + 1.0f;
        rngf = fminf(fmaxf(rngf, 1.0f), (float)NCLS);
        out[OMB + n] = (t == 1) ? 1.0f : 0.0f;
        out[OMS + n] = small_ ? 1.0f : 0.0f;
        out[OML + n] = (is_int && !small_) ? 1.0f : 0.0f;
        out[OOF + n] = off;
        out[ORG + n] = (float)((int)rngf);
    }
}

// ---------------- per-head MLP kernel ----------------
struct HeadP {
    const unsigned short* W1e;
    const float* b1e;
    const unsigned short* W2b;
    const float* b2;
    const float* Wh;
    const float* bh;
    int nc;
    int obase;
};

// software-pipelined GEMM, A and B both from global (row-major, k-contiguous)
__device__ __forceinline__ void gemm_gp(const unsigned short* A, const unsigned short* W,
                                        f32x4 (&acc)[2][8]) {
    bf16x8 a0[2], a1[2], b[2][8];
    a0[0] = *(const bf16x8*)(A);
    a1[0] = *(const bf16x8*)(A + 16 * 256);
#pragma unroll
    for (int t = 0; t < 8; ++t) b[0][t] = *(const bf16x8*)(W + t * 4096);
#pragma unroll
    for (int k = 0; k < 8; ++k) {
        int cur = k & 1, nxt = cur ^ 1;
        if (k < 7) {
            const unsigned short* A2 = A + (k + 1) * 32;
            const unsigned short* W2 = W + (k + 1) * 32;
            a0[nxt] = *(const bf16x8*)(A2);
            a1[nxt] = *(const bf16x8*)(A2 + 16 * 256);
#pragma unroll
            for (int t = 0; t < 8; ++t) b[nxt][t] = *(const bf16x8*)(W2 + t * 4096);
        }
#pragma unroll
        for (int t = 0; t < 8; ++t) {
            acc[0][t] = __builtin_amdgcn_mfma_f32_16x16x32_bf16(a0[cur], b[cur][t], acc[0][t], 0, 0, 0);
            acc[1][t] = __builtin_amdgcn_mfma_f32_16x16x32_bf16(a1[cur], b[cur][t], acc[1][t], 0, 0, 0);
        }
    }
}

// software-pipelined GEMM, A from swizzled LDS, B from global
__device__ __forceinline__ void gemm_lp(const unsigned short* src, const unsigned short* W,
                                        int M0, int l15, int lq, f32x4 (&acc)[2][8]) {
    int r0 = M0 + l15, r1 = r0 + 16;
    int sw0 = swz(r0), sw1 = swz(r1);
    bf16x8 a0[2], a1[2], b[2][8];
    a0[0] = *(const bf16x8*)(src + r0 * 256 + ((lq ^ sw0) << 3));
    a1[0] = *(const bf16x8*)(src + r1 * 256 + ((lq ^ sw1) << 3));
#pragma unroll
    for (int t = 0; t < 8; ++t) b[0][t] = *(const bf16x8*)(W + t * 4096);
#pragma unroll
    for (int k = 0; k < 8; ++k) {
        int cur = k & 1, nxt = cur ^ 1;
        if (k < 7) {
            int ch = (k + 1) * 4 + lq;
            a0[nxt] = *(const bf16x8*)(src + r0 * 256 + (((ch) ^ sw0) << 3));
            a1[nxt] = *(const bf16x8*)(src + r1 * 256 + (((ch) ^ sw1) << 3));
            const unsigned short* W2 = W + (k + 1) * 32;
#pragma unroll
            for (int t = 0; t < 8; ++t) b[nxt][t] = *(const bf16x8*)(W2 + t * 4096);
        }
#pragma unroll
        for (int t = 0; t < 8; ++t) {
            acc[0][t] = __builtin_amdgcn_mfma_f32_16x16x32_bf16(a0[cur], b[cur][t], acc[0][t], 0, 0, 0);
            acc[1][t] = __builtin_amdgcn_mfma_f32_16x16x32_bf16(a1[cur], b[cur][t], acc[1][t], 0, 0, 0);
        }
    }
}

__global__ __launch_bounds__(256, 3)
void k_heads(const unsigned short* __restrict__ zhat, const float* __restrict__ zwh,
             const float* __restrict__ ranges,
             HeadP h0, HeadP h1p, HeadP h2p,
             float* __restrict__ opb, float* __restrict__ olg, float* __restrict__ opl) {
    __shared__ unsigned short hl[64 * 256];   // 32 KB (reused as partials)
    __shared__ float whs[NCLS * 256];         // 11 KB
    __shared__ float b1s[DD], b2s[DD];
    __shared__ float zws[64 * NCLS];
    __shared__ float bhs[NCLS];

    int head = blockIdx.x / NT;
    int tile = blockIdx.x % NT;
    HeadP hp = (head == 0) ? h0 : ((head == 1) ? h1p : h2p);
    int nc = hp.nc;
    int n0 = tile * 64;
    int tid = threadIdx.x;

    // stage weights/biases/zwh into LDS
    for (int i = tid; i < nc * DD; i += 256) whs[i] = hp.Wh[i];
    b1s[tid] = hp.b1e[tid];
    b2s[tid] = hp.b2[tid];
    for (int i = tid; i < 64 * nc; i += 256) {
        int r = i / nc, o = i - r * nc;
        int n = n0 + r;
        zws[i] = (n < NV) ? zwh[(size_t)n * 16 + hp.obase + o] : 0.f;
    }
    if (tid < nc) bhs[tid] = hp.bh[tid];

    int lane = tid & 63, wv = tid >> 6;
    int wr = wv >> 1, wc = wv & 1;
    int l15 = lane & 15, lq = lane >> 4;
    int M0 = wr * 32;
    float* pb = (float*)hl;

    f32x4 acc[2][8];
#pragma unroll
    for (int i = 0; i < 2; ++i)
#pragma unroll
        for (int t = 0; t < 8; ++t) acc[i][t] = f32x4{0.f, 0.f, 0.f, 0.f};

    // GEMM1: zhat @ W1e.T  (A straight from global, pipelined)
    const unsigned short* A0 = zhat + (size_t)(n0 + M0 + l15) * DD + lq * 8;
    const unsigned short* Wb1 = hp.W1e + (wc * 128 + l15) * DD + lq * 8;
    gemm_gp(A0, Wb1, acc);
    __syncthreads();   // covers staging too (staging loads finished long ago)

    // epilogue 1: +b1e, gelu -> hl (bf16, swizzled)
#pragma unroll
    for (int t = 0; t < 8; ++t) {
        int col = wc * 128 + 16 * t + l15;
        float bias = b1s[col];
#pragma unroll
        for (int i = 0; i < 2; ++i) {
#pragma unroll
            for (int r = 0; r < 4; ++r) {
                int row = M0 + 16 * i + lq * 4 + r;
                hl[lidx(row, col)] = f2b(gelu_f(acc[i][t][r] + bias));
            }
        }
    }
    __syncthreads();

    // GEMM2: h1 @ W2.T (A from LDS, pipelined)
#pragma unroll
    for (int i = 0; i < 2; ++i)
#pragma unroll
        for (int t = 0; t < 8; ++t) acc[i][t] = f32x4{0.f, 0.f, 0.f, 0.f};
    const unsigned short* Wb2 = hp.W2b + (wc * 128 + l15) * DD + lq * 8;
    gemm_lp(hl, Wb2, M0, l15, lq, acc);

    // epilogue 2: h = gelu(acc + b2)  (residual folded into zws)
#pragma unroll
    for (int t = 0; t < 8; ++t) {
        int col = wc * 128 + 16 * t + l15;
        float bias = b2s[col];
#pragma unroll
        for (int i = 0; i < 2; ++i) {
#pragma unroll
            for (int r = 0; r < 4; ++r) {
                acc[i][t][r] = gelu_f(acc[i][t][r] + bias);
            }
        }
    }
    __syncthreads();  // hl free now

    // head projection: partial dots over this wave's column half (Wh from LDS)
    for (int o = 0; o < nc; ++o) {
#pragma unroll
        for (int i = 0; i < 2; ++i) {
            float p0 = 0.f, p1 = 0.f, p2 = 0.f, p3 = 0.f;
#pragma unroll
            for (int t = 0; t < 8; ++t) {
                float w = whs[o * DD + wc * 128 + 16 * t + l15];
                p0 += acc[i][t][0] * w; p1 += acc[i][t][1] * w;
                p2 += acc[i][t][2] * w; p3 += acc[i][t][3] * w;
            }
#pragma unroll
            for (int m = 1; m < 16; m <<= 1) {
                p0 += __shfl_xor(p0, m); p1 += __shfl_xor(p1, m);
                p2 += __shfl_xor(p2, m); p3 += __shfl_xor(p3, m);
            }
            if (l15 == 0) {
                int rb = M0 + 16 * i + lq * 4;
                pb[(rb + 0) * 128 + 2 * o + wc] = p0;
                pb[(rb + 1) * 128 + 2 * o + wc] = p1;
                pb[(rb + 2) * 128 + 2 * o + wc] = p2;
                pb[(rb + 3) * 128 + 2 * o + wc] = p3;
            }
        }
    }
    __syncthreads();

    // combine halves + zwh + bh + activation/mask + store
    for (int idx = tid; idx < 64 * nc; idx += 256) {
        int row, o;
        if (nc == 1) { row = idx; o = 0; }
        else { row = idx / NCLS; o = idx - row * NCLS; }
        int n = n0 + row;
        if (n < NV) {
            float val = pb[row * 128 + 2 * o] + pb[row * 128 + 2 * o + 1]
                      + zws[row * nc + o] + bhs[o];
            if (head == 0)      opb[n] = 1.f / (1.f + expf(-val));
            else if (head == 2) opl[n] = val;
            else {
                int rng = (int)ranges[n];
                olg[n * NCLS + o] = (o < rng) ? val : -1e9f;
            }
        }
    }
}

extern "C" void kernel_launch(void* const* d_in, const int* in_sizes, int n_in,
                              void* d_out, int out_size, void* d_ws, size_t ws_size,
                              hipStream_t stream) {
    const float* et = (const float*)d_in[0];
    const int*   vb = (const int*)d_in[1];
    const float* aw = (const float*)d_in[2];
    const int*   vt = (const int*)d_in[3];
    const float* z0 = (const float*)d_in[4];
    const float* vf = (const float*)d_in[5];
    const float* Wp = (const float*)d_in[6];
    const float* bp = (const float*)d_in[7];
    const float* fg = (const float*)d_in[8];
    const float* fb = (const float*)d_in[9];
    float* out = (float*)d_out;

    char* ws = (char*)d_ws;
    float* proj          = (float*)ws;                        // 262144 B
    float* b1e           = (float*)(ws + 262144);             // 3072 B (+pad)
    unsigned short* W1e  = (unsigned short*)(ws + 265216);    // 393216 B
    unsigned short* W2b  = (unsigned short*)(ws + 658432);    // 393216 B
    unsigned short* zhat = (unsigned short*)(ws + 1051648);   // 30016*512 B
    float* zwh           = (float*)(ws + 16419840);           // 30016*64 B

    k_proj<<<256, 256, 0, stream>>>(et, Wp, bp, proj);

    WP wps[3];
    for (int h = 0; h < 3; ++h) {
        wps[h].W1 = (const float*)d_in[12 + 8 * h];
        wps[h].ng = (const float*)d_in[10 + 8 * h];
        wps[h].nb = (const float*)d_in[11 + 8 * h];
        wps[h].b1 = (const float*)d_in[13 + 8 * h];
        wps[h].W2 = (const float*)d_in[14 + 8 * h];
        wps[h].W1e = W1e + h * 65536;
        wps[h].W2b = W2b + h * 65536;
        wps[h].b1e = b1e + h * 256;
    }
    k_wprep<<<dim3(256, 3), 256, 0, stream>>>(wps[0], wps[1], wps[2]);

    k_zout<<<7500, 256, 0, stream>>>(proj, vb, aw, z0, fg, fb,
                                     (const float*)d_in[16], (const float*)d_in[24],
                                     (const float*)d_in[32], vf, vt,
                                     out, zhat, zwh);

    HeadP hps[3];
    int obase[3] = {0, 1, 12};
    for (int h = 0; h < 3; ++h) {
        hps[h].W1e = W1e + h * 65536;
        hps[h].b1e = b1e + h * 256;
        hps[h].W2b = W2b + h * 65536;
        hps[h].b2  = (const float*)d_in[15 + 8 * h];
        hps[h].Wh  = (const float*)d_in[16 + 8 * h];
        hps[h].bh  = (const float*)d_in[17 + 8 * h];
        hps[h].nc  = (h == 1) ? NCLS : 1;
        hps[h].obase = obase[h];
    }
    k_heads<<<3 * NT, 256, 0, stream>>>(zhat, zwh, out + ORG,
                                        hps[0], hps[1], hps[2],
                                        out + OPB, out + OLG, out + OPL);
}

// Round 5
// 295.776 us; speedup vs baseline: 1.5746x; 1.0896x over previous
//
#include <hip/hip_runtime.h>
#include <math.h>

#define NV   30000
#define DD   256
#define KK   32
#define NCLS 11
#define NT   469   // row tiles of 64

// output layout (floats)
#define OZ  0
#define OPB 7680000
#define OLG 7710000
#define OPL 8040000
#define OMB 8070000
#define OMS 8100000
#define OML 8130000
#define OOF 8160000
#define ORG 8190000

typedef __bf16 bf16x8 __attribute__((ext_vector_type(8)));
typedef float  f32x4  __attribute__((ext_vector_type(4)));

__device__ __forceinline__ unsigned short f2b(float f) {
    unsigned u = __float_as_uint(f);
    u += 0x7fffu + ((u >> 16) & 1u);
    return (unsigned short)(u >> 16);
}

// gelu via A&S 7.1.26 erf approx (|eps|<=1.5e-7)
__device__ __forceinline__ float gelu_f(float x) {
    float y = fabsf(x) * 0.70710678118f;
    float t = __builtin_amdgcn_rcpf(__builtin_fmaf(0.3275911f, y, 1.0f));
    float p = t * (0.254829592f + t * (-0.284496736f + t * (1.421413741f +
              t * (-1.453152027f + t * 1.061405429f))));
    float e = __expf(-y * y);
    float erfa = __builtin_fmaf(-p, e, 1.0f);
    float erfv = copysignf(erfa, x);
    return 0.5f * x * (1.0f + erfv);
}

__device__ __forceinline__ int swz(int row) { return (row + (row >> 3)) & 7; }
__device__ __forceinline__ int lidx(int row, int col) {
    return row * 256 + ((((col) >> 3) ^ swz(row)) << 3) + (col & 7);
}

// ---------------- proj = evolved_tokens @ Wp.T + bp ----------------
__global__ void k_proj(const float* __restrict__ et, const float* __restrict__ Wp,
                       const float* __restrict__ bp, float* __restrict__ proj) {
    __shared__ float es[DD];
    int r = blockIdx.x, c = threadIdx.x;
    es[c] = et[r * DD + c];
    __syncthreads();
    const float4* w4 = (const float4*)(Wp + c * DD);
    float acc = bp[c];
#pragma unroll 16
    for (int d = 0; d < DD / 4; ++d) {
        float4 w = w4[d];
        acc += es[4 * d] * w.x + es[4 * d + 1] * w.y + es[4 * d + 2] * w.z + es[4 * d + 3] * w.w;
    }
    proj[r * DD + c] = acc;
}

// ---------------- merged weight prep (3 heads via blockIdx.y) ----------------
struct WP {
    const float *W1, *ng, *nb, *b1, *W2, *Wh;
    unsigned short *W1e, *W2b, *Whb;
    float *b1e;
    int nc;
};

__global__ void k_wprep(WP wa, WP wb, WP wc) {
    WP wp = (blockIdx.y == 0) ? wa : ((blockIdx.y == 1) ? wb : wc);
    int j = blockIdx.x, d = threadIdx.x;
    float v1 = wp.W1[j * DD + d];
    wp.W1e[j * DD + d] = f2b(v1 * wp.ng[d]);
    wp.W2b[j * DD + d] = f2b(wp.W2[j * DD + d]);
    if (j < 16) {
        float v = (j < wp.nc) ? wp.Wh[j * DD + d] : 0.f;
        wp.Whb[j * DD + d] = f2b(v);
    }
    float p = v1 * wp.nb[d];
#pragma unroll
    for (int m = 1; m < 64; m <<= 1) p += __shfl_xor(p, m);
    __shared__ float red[4];
    if ((d & 63) == 0) red[d >> 6] = p;
    __syncthreads();
    if (d == 0) wp.b1e[j] = wp.b1[j] + red[0] + red[1] + red[2] + red[3];
}

// ---- z_out = LN(einsum+z0); zhat bf16; masks fused ----
__global__ __launch_bounds__(256)
void k_zout(const float* __restrict__ proj, const int* __restrict__ vb,
            const float* __restrict__ aw, const float* __restrict__ z0,
            const float* __restrict__ g, const float* __restrict__ b,
            const float* __restrict__ vf, const int* __restrict__ vt,
            float* __restrict__ out, unsigned short* __restrict__ zhat) {
    int wv = threadIdx.x >> 6, lane = threadIdx.x & 63;
    int n = blockIdx.x * 4 + wv;
    if (n >= NV) return;
    int bidx = vb[n];
    float awv = aw[n * KK + (lane & 31)];
    const float4* pr = (const float4*)(proj + (size_t)bidx * KK * DD);
    float4 acc = ((const float4*)(z0 + (size_t)n * DD))[lane];
#pragma unroll 8
    for (int k = 0; k < KK; ++k) {
        float a = __shfl(awv, k);
        float4 p = pr[k * 64 + lane];
        acc.x += a * p.x; acc.y += a * p.y; acc.z += a * p.z; acc.w += a * p.w;
    }
    // LN1
    float s = acc.x + acc.y + acc.z + acc.w;
    float q = acc.x * acc.x + acc.y * acc.y + acc.z * acc.z + acc.w * acc.w;
#pragma unroll
    for (int m = 1; m < 64; m <<= 1) { s += __shfl_xor(s, m); q += __shfl_xor(q, m); }
    float mean = s * (1.f / DD);
    float var  = q * (1.f / DD) - mean * mean;
    float rs   = rsqrtf(var + 1e-5f);
    float4 g4 = ((const float4*)g)[lane], b4 = ((const float4*)b)[lane];
    float4 z;
    z.x = (acc.x - mean) * rs * g4.x + b4.x;
    z.y = (acc.y - mean) * rs * g4.y + b4.y;
    z.z = (acc.z - mean) * rs * g4.z + b4.z;
    z.w = (acc.w - mean) * rs * g4.w + b4.w;
    ((float4*)(out + OZ + (size_t)n * DD))[lane] = z;
    // LN2 (no affine) -> zhat bf16
    float s2 = z.x + z.y + z.z + z.w;
    float q2 = z.x * z.x + z.y * z.y + z.z * z.z + z.w * z.w;
#pragma unroll
    for (int m = 1; m < 64; m <<= 1) { s2 += __shfl_xor(s2, m); q2 += __shfl_xor(q2, m); }
    float m2 = s2 * (1.f / DD);
    float v2 = q2 * (1.f / DD) - m2 * m2;
    float r2 = rsqrtf(v2 + 1e-5f);
    ushort4 zh;
    zh.x = f2b((z.x - m2) * r2); zh.y = f2b((z.y - m2) * r2);
    zh.z = f2b((z.z - m2) * r2); zh.w = f2b((z.w - m2) * r2);
    *(ushort4*)(zhat + (size_t)n * DD + 4 * lane) = zh;
    // fused masks/offsets/ranges (lane 0)
    if (lane == 0) {
        float lb = vf[n * 23 + 21], ub = vf[n * 23 + 22];
        int t = vt[n];
        bool is_int = (t == 2);
        bool finite = (fabsf(lb) < 1e18f) && (fabsf(ub) < 1e18f);
        bool small_ = is_int && finite && (ub - lb <= 10.0f);
        float off = floorf(lb);
        float rngf = ceilf(ub) - off + 1.0f;
        rngf = fminf(fmaxf(rngf, 1.0f), (float)NCLS);
        out[OMB + n] = (t == 1) ? 1.0f : 0.0f;
        out[OMS + n] = small_ ? 1.0f : 0.0f;
        out[OML + n] = (is_int && !small_) ? 1.0f : 0.0f;
        out[OOF + n] = off;
        out[ORG + n] = (float)((int)rngf);
    }
}

// ---- zwh[n][3*16] = z_out @ Whb_all.T  (skinny MFMA GEMM) ----
__global__ __launch_bounds__(256)
void k_zwh(const float* __restrict__ zout, const unsigned short* __restrict__ Whb,
           float* __restrict__ zwh) {
    int wv = threadIdx.x >> 6, lane = threadIdx.x & 63;
    int l15 = lane & 15, lq = lane >> 4;
    int n0 = blockIdx.x * 64;
    int arow = n0 + wv * 16 + l15;
    const float* ap = zout + (size_t)arow * DD + lq * 8;
    f32x4 acc[3];
#pragma unroll
    for (int nt = 0; nt < 3; ++nt) acc[nt] = f32x4{0.f, 0.f, 0.f, 0.f};
#pragma unroll
    for (int ks = 0; ks < 8; ++ks) {
        float4 a0 = *(const float4*)(ap + ks * 32);
        float4 a1 = *(const float4*)(ap + ks * 32 + 4);
        bf16x8 a;
        a[0] = (__bf16)a0.x; a[1] = (__bf16)a0.y; a[2] = (__bf16)a0.z; a[3] = (__bf16)a0.w;
        a[4] = (__bf16)a1.x; a[5] = (__bf16)a1.y; a[6] = (__bf16)a1.z; a[7] = (__bf16)a1.w;
#pragma unroll
        for (int nt = 0; nt < 3; ++nt) {
            bf16x8 b = *(const bf16x8*)(Whb + (size_t)(nt * 16 + l15) * DD + ks * 32 + lq * 8);
            acc[nt] = __builtin_amdgcn_mfma_f32_16x16x32_bf16(a, b, acc[nt], 0, 0, 0);
        }
    }
    int orow = n0 + wv * 16 + lq * 4;
#pragma unroll
    for (int nt = 0; nt < 3; ++nt)
#pragma unroll
        for (int r = 0; r < 4; ++r)
            if (orow + r < NV) zwh[(size_t)(orow + r) * 48 + nt * 16 + l15] = acc[nt][r];
}

// ---------------- per-head MLP kernel ----------------
struct HeadP {
    const unsigned short *W1e, *W2b, *Whb;
    const float *b1e, *b2, *bh;
    int nc;
};

__global__ __launch_bounds__(256, 3)
void k_heads(const unsigned short* __restrict__ zhat, const float* __restrict__ zwh,
             const float* __restrict__ ranges,
             HeadP h0, HeadP h1p, HeadP h2p,
             float* __restrict__ opb, float* __restrict__ olg, float* __restrict__ opl) {
    __shared__ unsigned short hl[64 * 256];   // 32 KB: h1, then h, then partials
    __shared__ float b1s[DD], b2s[DD];
    __shared__ float zws[64 * 16];
    __shared__ float bhs[16];

    int head = blockIdx.x / NT;
    int tile = blockIdx.x % NT;
    HeadP hp = (head == 0) ? h0 : ((head == 1) ? h1p : h2p);
    int nc = hp.nc;
    int n0 = tile * 64;
    int tid = threadIdx.x;

    b1s[tid] = hp.b1e[tid];
    b2s[tid] = hp.b2[tid];
#pragma unroll
    for (int i = tid; i < 64 * 16; i += 256) {
        int rr = i >> 4, o = i & 15;
        int n = n0 + rr;
        zws[i] = (n < NV) ? zwh[(size_t)n * 48 + head * 16 + o] : 0.f;
    }
    if (tid < 16) bhs[tid] = (tid < nc) ? hp.bh[tid] : 0.f;

    int lane = tid & 63, wv = tid >> 6;
    int l15 = lane & 15, lq = lane >> 4;
    int nb0 = wv * 64;

    f32x4 acc[4][4];
#pragma unroll
    for (int mt = 0; mt < 4; ++mt)
#pragma unroll
        for (int nt = 0; nt < 4; ++nt) acc[mt][nt] = f32x4{0.f, 0.f, 0.f, 0.f};

    // ---- GEMM1: zhat @ W1e.T  (A global, B global, double-buffered regs) ----
    {
        const unsigned short* Ab = zhat + (size_t)(n0 + l15) * DD + lq * 8;
        const unsigned short* Bb = hp.W1e + (size_t)(nb0 + l15) * DD + lq * 8;
        bf16x8 a[2][4], b[2][4];
#pragma unroll
        for (int mt = 0; mt < 4; ++mt) a[0][mt] = *(const bf16x8*)(Ab + mt * 16 * DD);
#pragma unroll
        for (int nt = 0; nt < 4; ++nt) b[0][nt] = *(const bf16x8*)(Bb + nt * 16 * DD);
#pragma unroll
        for (int ks = 0; ks < 8; ++ks) {
            int cur = ks & 1, nxt = cur ^ 1;
            if (ks < 7) {
                int ko = (ks + 1) * 32;
#pragma unroll
                for (int mt = 0; mt < 4; ++mt) a[nxt][mt] = *(const bf16x8*)(Ab + mt * 16 * DD + ko);
#pragma unroll
                for (int nt = 0; nt < 4; ++nt) b[nxt][nt] = *(const bf16x8*)(Bb + nt * 16 * DD + ko);
            }
#pragma unroll
            for (int nt = 0; nt < 4; ++nt)
#pragma unroll
                for (int mt = 0; mt < 4; ++mt)
                    acc[mt][nt] = __builtin_amdgcn_mfma_f32_16x16x32_bf16(a[cur][mt], b[cur][nt], acc[mt][nt], 0, 0, 0);
        }
    }
    __syncthreads();   // also covers b1s/b2s staging

    // epilogue 1: +b1e, gelu -> hl (bf16, swizzled)
#pragma unroll
    for (int nt = 0; nt < 4; ++nt) {
        int col = nb0 + nt * 16 + l15;
        float bias = b1s[col];
#pragma unroll
        for (int mt = 0; mt < 4; ++mt)
#pragma unroll
            for (int r = 0; r < 4; ++r) {
                int row = mt * 16 + lq * 4 + r;
                hl[lidx(row, col)] = f2b(gelu_f(acc[mt][nt][r] + bias));
            }
    }
    __syncthreads();

    // ---- GEMM2: h1 @ W2.T  (A from LDS, B global, double-buffered regs) ----
#pragma unroll
    for (int mt = 0; mt < 4; ++mt)
#pragma unroll
        for (int nt = 0; nt < 4; ++nt) acc[mt][nt] = f32x4{0.f, 0.f, 0.f, 0.f};
    {
        const unsigned short* Bb = hp.W2b + (size_t)(nb0 + l15) * DD + lq * 8;
        bf16x8 a[2][4], b[2][4];
#pragma unroll
        for (int mt = 0; mt < 4; ++mt) {
            int row = mt * 16 + l15;
            int ph = ((lq & 7) ^ swz(row));
            a[0][mt] = *(const bf16x8*)(hl + row * 256 + ph * 8);
        }
#pragma unroll
        for (int nt = 0; nt < 4; ++nt) b[0][nt] = *(const bf16x8*)(Bb + nt * 16 * DD);
#pragma unroll
        for (int ks = 0; ks < 8; ++ks) {
            int cur = ks & 1, nxt = cur ^ 1;
            if (ks < 7) {
                int ck = (ks + 1) * 4 + lq;
#pragma unroll
                for (int mt = 0; mt < 4; ++mt) {
                    int row = mt * 16 + l15;
                    int ph = (ck & ~7) | ((ck & 7) ^ swz(row));
                    a[nxt][mt] = *(const bf16x8*)(hl + row * 256 + ph * 8);
                }
#pragma unroll
                for (int nt = 0; nt < 4; ++nt) b[nxt][nt] = *(const bf16x8*)(Bb + nt * 16 * DD + (ks + 1) * 32);
            }
#pragma unroll
            for (int nt = 0; nt < 4; ++nt)
#pragma unroll
                for (int mt = 0; mt < 4; ++mt)
                    acc[mt][nt] = __builtin_amdgcn_mfma_f32_16x16x32_bf16(a[cur][mt], b[cur][nt], acc[mt][nt], 0, 0, 0);
        }
    }

    // epilogue 2 in regs: h = gelu(acc + b2)
#pragma unroll
    for (int nt = 0; nt < 4; ++nt) {
        float bias = b2s[nb0 + nt * 16 + l15];
#pragma unroll
        for (int mt = 0; mt < 4; ++mt)
#pragma unroll
            for (int r = 0; r < 4; ++r)
                acc[mt][nt][r] = gelu_f(acc[mt][nt][r] + bias);
    }
    __syncthreads();   // everyone done reading hl (h1)

    // write h (bf16) into own column stripe of hl
#pragma unroll
    for (int nt = 0; nt < 4; ++nt) {
        int col = nb0 + nt * 16 + l15;
#pragma unroll
        for (int mt = 0; mt < 4; ++mt)
#pragma unroll
            for (int r = 0; r < 4; ++r) {
                int row = mt * 16 + lq * 4 + r;
                hl[lidx(row, col)] = f2b(acc[mt][nt][r]);
            }
    }

    // ---- projection via MFMA: partial over own 64 cols ----
    f32x4 accP[4];
#pragma unroll
    for (int mt = 0; mt < 4; ++mt) accP[mt] = f32x4{0.f, 0.f, 0.f, 0.f};
    {
        const unsigned short* Wb = hp.Whb + (size_t)l15 * DD + nb0 + lq * 8;
#pragma unroll
        for (int ks = 0; ks < 2; ++ks) {
            bf16x8 bP = *(const bf16x8*)(Wb + ks * 32);
#pragma unroll
            for (int mt = 0; mt < 4; ++mt) {
                int row = mt * 16 + l15;
                int ck = (nb0 >> 3) + ks * 4 + lq;
                int ph = (ck & ~7) | ((ck & 7) ^ swz(row));
                bf16x8 aP = *(const bf16x8*)(hl + row * 256 + ph * 8);
                accP[mt] = __builtin_amdgcn_mfma_f32_16x16x32_bf16(aP, bP, accP[mt], 0, 0, 0);
            }
        }
    }
    // write float partials into own stripe (row-major: 16 floats fit in 64-col stripe)
#pragma unroll
    for (int mt = 0; mt < 4; ++mt) {
        int row = mt * 16 + lq * 4;
#pragma unroll
        for (int r = 0; r < 4; ++r) {
            float* pp = (float*)(hl + (row + r) * 256 + nb0);
            pp[l15] = accP[mt][r];
        }
    }
    __syncthreads();

    // combine 4 stripes + zwh + bh + activation/mask + store
    for (int idx = tid; idx < 64 * nc; idx += 256) {
        int row, o;
        if (nc == 1) { row = idx; o = 0; }
        else { row = idx / NCLS; o = idx - row * NCLS; }
        int n = n0 + row;
        if (n < NV) {
            float val = bhs[o] + zws[row * 16 + o];
#pragma unroll
            for (int w2 = 0; w2 < 4; ++w2)
                val += ((const float*)(hl + row * 256 + w2 * 64))[o];
            if (head == 0)      opb[n] = 1.f / (1.f + expf(-val));
            else if (head == 2) opl[n] = val;
            else {
                int rng = (int)ranges[n];
                olg[n * NCLS + o] = (o < rng) ? val : -1e9f;
            }
        }
    }
}

extern "C" void kernel_launch(void* const* d_in, const int* in_sizes, int n_in,
                              void* d_out, int out_size, void* d_ws, size_t ws_size,
                              hipStream_t stream) {
    const float* et = (const float*)d_in[0];
    const int*   vb = (const int*)d_in[1];
    const float* aw = (const float*)d_in[2];
    const int*   vt = (const int*)d_in[3];
    const float* z0 = (const float*)d_in[4];
    const float* vf = (const float*)d_in[5];
    const float* Wp = (const float*)d_in[6];
    const float* bp = (const float*)d_in[7];
    const float* fg = (const float*)d_in[8];
    const float* fb = (const float*)d_in[9];
    float* out = (float*)d_out;

    char* ws = (char*)d_ws;
    float* proj          = (float*)ws;                        // 262144 B
    float* b1e           = (float*)(ws + 262144);             // 3072 B (+pad)
    unsigned short* W1e  = (unsigned short*)(ws + 265216);    // 393216 B
    unsigned short* W2b  = (unsigned short*)(ws + 658432);    // 393216 B
    unsigned short* Whb  = (unsigned short*)(ws + 1051648);   // 24576 B
    unsigned short* zhat = (unsigned short*)(ws + 1076224);   // 30016*512 B
    float* zwh           = (float*)(ws + 16444416);           // 30016*192 B -> 22.2 MB

    k_proj<<<256, 256, 0, stream>>>(et, Wp, bp, proj);

    WP wps[3];
    for (int h = 0; h < 3; ++h) {
        wps[h].W1 = (const float*)d_in[12 + 8 * h];
        wps[h].ng = (const float*)d_in[10 + 8 * h];
        wps[h].nb = (const float*)d_in[11 + 8 * h];
        wps[h].b1 = (const float*)d_in[13 + 8 * h];
        wps[h].W2 = (const float*)d_in[14 + 8 * h];
        wps[h].Wh = (const float*)d_in[16 + 8 * h];
        wps[h].W1e = W1e + h * 65536;
        wps[h].W2b = W2b + h * 65536;
        wps[h].Whb = Whb + h * 4096;
        wps[h].b1e = b1e + h * 256;
        wps[h].nc  = (h == 1) ? NCLS : 1;
    }
    k_wprep<<<dim3(256, 3), 256, 0, stream>>>(wps[0], wps[1], wps[2]);

    k_zout<<<7500, 256, 0, stream>>>(proj, vb, aw, z0, fg, fb, vf, vt, out, zhat);

    k_zwh<<<NT, 256, 0, stream>>>(out + OZ, Whb, zwh);

    HeadP hps[3];
    for (int h = 0; h < 3; ++h) {
        hps[h].W1e = W1e + h * 65536;
        hps[h].W2b = W2b + h * 65536;
        hps[h].Whb = Whb + h * 4096;
        hps[h].b1e = b1e + h * 256;
        hps[h].b2  = (const float*)d_in[15 + 8 * h];
        hps[h].bh  = (const float*)d_in[17 + 8 * h];
        hps[h].nc  = (h == 1) ? NCLS : 1;
    }
    k_heads<<<3 * NT, 256, 0, stream>>>(zhat, zwh, out + ORG,
                                        hps[0], hps[1], hps[2],
                                        out + OPB, out + OLG, out + OPL);
}

// Round 6
// 280.224 us; speedup vs baseline: 1.6620x; 1.0555x over previous
//
#include <hip/hip_runtime.h>
#include <math.h>

#define NV   30000
#define DD   256
#define KK   32
#define NCLS 11
#define NT   469   // row tiles of 64

// output layout (floats)
#define OZ  0
#define OPB 7680000
#define OLG 7710000
#define OPL 8040000
#define OMB 8070000
#define OMS 8100000
#define OML 8130000
#define OOF 8160000
#define ORG 8190000

typedef __bf16 bf16x8 __attribute__((ext_vector_type(8)));
typedef float  f32x4  __attribute__((ext_vector_type(4)));

__device__ __forceinline__ unsigned short f2b(float f) {
    unsigned u = __float_as_uint(f);
    u += 0x7fffu + ((u >> 16) & 1u);
    return (unsigned short)(u >> 16);
}

// gelu via A&S 7.1.26 erf approx (|eps|<=1.5e-7)
__device__ __forceinline__ float gelu_f(float x) {
    float y = fabsf(x) * 0.70710678118f;
    float t = __builtin_amdgcn_rcpf(__builtin_fmaf(0.3275911f, y, 1.0f));
    float p = t * (0.254829592f + t * (-0.284496736f + t * (1.421413741f +
              t * (-1.453152027f + t * 1.061405429f))));
    float e = __expf(-y * y);
    float erfa = __builtin_fmaf(-p, e, 1.0f);
    float erfv = copysignf(erfa, x);
    return 0.5f * x * (1.0f + erfv);
}

__device__ __forceinline__ int swz(int row) { return (row + (row >> 3)) & 7; }
__device__ __forceinline__ int lidx(int row, int col) {
    return row * 256 + ((((col) >> 3) ^ swz(row)) << 3) + (col & 7);
}

// ---------------- merged prep: y==0 proj, y=1..3 per-head weight prep ----------------
struct WP {
    const float *W1, *ng, *nb, *b1, *W2, *Wh;
    unsigned short *W1e, *W2b, *Whb;
    float *b1e, *swh;
    int nc;
};

__global__ void k_prep(const float* __restrict__ et, const float* __restrict__ Wp,
                       const float* __restrict__ bp, float* __restrict__ proj,
                       WP wa, WP wb, WP wc) {
    __shared__ float es[DD];
    __shared__ float red[4], red2[4];
    if (blockIdx.y == 0) {
        int r = blockIdx.x, c = threadIdx.x;
        es[c] = et[r * DD + c];
        __syncthreads();
        const float4* w4 = (const float4*)(Wp + c * DD);
        float acc = bp[c];
#pragma unroll 16
        for (int d = 0; d < DD / 4; ++d) {
            float4 w = w4[d];
            acc += es[4 * d] * w.x + es[4 * d + 1] * w.y + es[4 * d + 2] * w.z + es[4 * d + 3] * w.w;
        }
        proj[r * DD + c] = acc;
        return;
    }
    WP wp = (blockIdx.y == 1) ? wa : ((blockIdx.y == 2) ? wb : wc);
    int j = blockIdx.x, d = threadIdx.x;
    float v1 = wp.W1[j * DD + d];
    wp.W1e[j * DD + d] = f2b(v1 * wp.ng[d]);
    wp.W2b[j * DD + d] = f2b(wp.W2[j * DD + d]);
    float p2 = 0.f;
    if (j < 16) {
        p2 = (j < wp.nc) ? wp.Wh[j * DD + d] : 0.f;
        wp.Whb[j * DD + d] = f2b(p2);
    }
    float p = v1 * wp.nb[d];
#pragma unroll
    for (int m = 1; m < 64; m <<= 1) { p += __shfl_xor(p, m); p2 += __shfl_xor(p2, m); }
    if ((d & 63) == 0) { red[d >> 6] = p; red2[d >> 6] = p2; }
    __syncthreads();
    if (d == 0) {
        wp.b1e[j] = wp.b1[j] + red[0] + red[1] + red[2] + red[3];
        if (j < 16) wp.swh[j] = red2[0] + red2[1] + red2[2] + red2[3];
    }
}

// ---- z_out = LN(einsum+z0); zhat bf16 (pre-swizzled tiles); zstat=(sigma,mu); masks ----
__global__ __launch_bounds__(256)
void k_zout(const float* __restrict__ proj, const int* __restrict__ vb,
            const float* __restrict__ aw, const float* __restrict__ z0,
            const float* __restrict__ g, const float* __restrict__ b,
            const float* __restrict__ vf, const int* __restrict__ vt,
            float* __restrict__ out, unsigned short* __restrict__ zhat,
            float2* __restrict__ zstat) {
    int wv = threadIdx.x >> 6, lane = threadIdx.x & 63;
    int n = blockIdx.x * 4 + wv;
    if (n >= NV) return;
    int bidx = vb[n];
    float awv = aw[n * KK + (lane & 31)];
    const float4* pr = (const float4*)(proj + (size_t)bidx * KK * DD);
    float4 acc = ((const float4*)(z0 + (size_t)n * DD))[lane];
#pragma unroll 8
    for (int k = 0; k < KK; ++k) {
        float a = __shfl(awv, k);
        float4 p = pr[k * 64 + lane];
        acc.x += a * p.x; acc.y += a * p.y; acc.z += a * p.z; acc.w += a * p.w;
    }
    // LN1
    float s = acc.x + acc.y + acc.z + acc.w;
    float q = acc.x * acc.x + acc.y * acc.y + acc.z * acc.z + acc.w * acc.w;
#pragma unroll
    for (int m = 1; m < 64; m <<= 1) { s += __shfl_xor(s, m); q += __shfl_xor(q, m); }
    float mean = s * (1.f / DD);
    float var  = q * (1.f / DD) - mean * mean;
    float rs   = rsqrtf(var + 1e-5f);
    float4 g4 = ((const float4*)g)[lane], b4 = ((const float4*)b)[lane];
    float4 z;
    z.x = (acc.x - mean) * rs * g4.x + b4.x;
    z.y = (acc.y - mean) * rs * g4.y + b4.y;
    z.z = (acc.z - mean) * rs * g4.z + b4.z;
    z.w = (acc.w - mean) * rs * g4.w + b4.w;
    ((float4*)(out + OZ + (size_t)n * DD))[lane] = z;
    // LN2 (no affine) -> zhat bf16, pre-swizzled tile layout
    float s2 = z.x + z.y + z.z + z.w;
    float q2 = z.x * z.x + z.y * z.y + z.z * z.z + z.w * z.w;
#pragma unroll
    for (int m = 1; m < 64; m <<= 1) { s2 += __shfl_xor(s2, m); q2 += __shfl_xor(q2, m); }
    float m2 = s2 * (1.f / DD);
    float v2 = q2 * (1.f / DD) - m2 * m2;
    float r2 = rsqrtf(v2 + 1e-5f);
    ushort4 zh;
    zh.x = f2b((z.x - m2) * r2); zh.y = f2b((z.y - m2) * r2);
    zh.z = f2b((z.z - m2) * r2); zh.w = f2b((z.w - m2) * r2);
    int rl = n & 63;
    int c = lane >> 1;
    int pc = (c & ~7) | ((c & 7) ^ swz(rl));
    *(ushort4*)(zhat + (size_t)(n & ~63) * 256 + rl * 256 + pc * 8 + (lane & 1) * 4) = zh;
    if (lane == 0) {
        // sigma = sqrt(v2+eps) = (v2+eps)*rsqrt(v2+eps); z = zhat*sigma + mu
        zstat[n] = make_float2((v2 + 1e-5f) * r2, m2);
        float lb = vf[n * 23 + 21], ub = vf[n * 23 + 22];
        int t = vt[n];
        bool is_int = (t == 2);
        bool finite = (fabsf(lb) < 1e18f) && (fabsf(ub) < 1e18f);
        bool small_ = is_int && finite && (ub - lb <= 10.0f);
        float off = floorf(lb);
        float rngf = ceilf(ub) - off + 1.0f;
        rngf = fminf(fmaxf(rngf, 1.0f), (float)NCLS);
        out[OMB + n] = (t == 1) ? 1.0f : 0.0f;
        out[OMS + n] = small_ ? 1.0f : 0.0f;
        out[OML + n] = (is_int && !small_) ? 1.0f : 0.0f;
        out[OOF + n] = off;
        out[ORG + n] = (float)((int)rngf);
    }
}

// ---------------- per-head MLP kernel ----------------
struct HeadP {
    const unsigned short *W1e, *W2b, *Whb;
    const float *b1e, *b2, *bh, *swh;
    int nc;
};

__global__ __launch_bounds__(256, 3)
void k_heads(const unsigned short* __restrict__ zhat, const float2* __restrict__ zstat,
             const float* __restrict__ ranges,
             HeadP h0, HeadP h1p, HeadP h2p,
             float* __restrict__ opb, float* __restrict__ olg, float* __restrict__ opl) {
    __shared__ unsigned short hl[64 * 256];   // 32 KB: zhat tile -> h1 -> h -> partials
    __shared__ float b1s[DD], b2s[DD];
    __shared__ float rs2s[64], m2s[64];
    __shared__ float swhs[16], bhs[16];

    int head = blockIdx.x / NT;
    int tile = blockIdx.x % NT;
    HeadP hp = (head == 0) ? h0 : ((head == 1) ? h1p : h2p);
    int nc = hp.nc;
    int n0 = tile * 64;
    int tid = threadIdx.x;

    // stage zhat tile (pre-swizzled -> straight copy) + biases + stats
    {
        const uint4* src = (const uint4*)(zhat + (size_t)n0 * 256);
        uint4* dst = (uint4*)hl;
#pragma unroll
        for (int j = 0; j < 8; ++j) dst[tid + j * 256] = src[tid + j * 256];
    }
    b1s[tid] = hp.b1e[tid];
    b2s[tid] = hp.b2[tid];
    if (tid < 64) {
        int n = n0 + tid;
        float2 st = (n < NV) ? zstat[n] : make_float2(0.f, 0.f);
        rs2s[tid] = st.x; m2s[tid] = st.y;
    } else if (tid < 80) {
        swhs[tid - 64] = hp.swh[tid - 64];
    } else if (tid < 96) {
        int o = tid - 80;
        bhs[o] = (o < nc) ? hp.bh[o] : 0.f;
    }

    int lane = tid & 63, wv = tid >> 6;
    int l15 = lane & 15, lq = lane >> 4;
    int nb0 = wv * 64;

    f32x4 acc[4][4];
#pragma unroll
    for (int mt = 0; mt < 4; ++mt)
#pragma unroll
        for (int nt = 0; nt < 4; ++nt) acc[mt][nt] = f32x4{0.f, 0.f, 0.f, 0.f};

    __syncthreads();

    // ---- GEMM1: zhat(LDS) @ W1e.T(global, depth-3 ring) ----
    {
        const unsigned short* Bb = hp.W1e + (size_t)(nb0 + l15) * DD + lq * 8;
        bf16x8 b[3][4], a[2][4];
#pragma unroll
        for (int s = 0; s < 3; ++s)
#pragma unroll
            for (int nt = 0; nt < 4; ++nt) b[s][nt] = *(const bf16x8*)(Bb + nt * 16 * DD + s * 32);
#pragma unroll
        for (int mt = 0; mt < 4; ++mt) {
            int row = mt * 16 + l15;
            int ph = (lq & 7) ^ swz(row);
            a[0][mt] = *(const bf16x8*)(hl + row * 256 + ph * 8);
        }
#pragma unroll
        for (int ks = 0; ks < 8; ++ks) {
            int cur = ks & 1, sl = ks % 3;
            if (ks < 7) {
                int ck = (ks + 1) * 4 + lq;
#pragma unroll
                for (int mt = 0; mt < 4; ++mt) {
                    int row = mt * 16 + l15;
                    int ph = (ck & ~7) | ((ck & 7) ^ swz(row));
                    a[cur ^ 1][mt] = *(const bf16x8*)(hl + row * 256 + ph * 8);
                }
            }
#pragma unroll
            for (int nt = 0; nt < 4; ++nt)
#pragma unroll
                for (int mt = 0; mt < 4; ++mt)
                    acc[mt][nt] = __builtin_amdgcn_mfma_f32_16x16x32_bf16(a[cur][mt], b[sl][nt], acc[mt][nt], 0, 0, 0);
            if (ks + 3 < 8) {
#pragma unroll
                for (int nt = 0; nt < 4; ++nt)
                    b[sl][nt] = *(const bf16x8*)(Bb + nt * 16 * DD + (ks + 3) * 32);
            }
        }
    }
    __syncthreads();   // all waves done reading zhat tile

    // epilogue 1: +b1e, gelu -> hl (bf16, swizzled)
#pragma unroll
    for (int nt = 0; nt < 4; ++nt) {
        int col = nb0 + nt * 16 + l15;
        float bias = b1s[col];
#pragma unroll
        for (int mt = 0; mt < 4; ++mt)
#pragma unroll
            for (int r = 0; r < 4; ++r) {
                int row = mt * 16 + lq * 4 + r;
                hl[lidx(row, col)] = f2b(gelu_f(acc[mt][nt][r] + bias));
            }
    }
    __syncthreads();

    // ---- GEMM2: h1(LDS) @ W2.T(global, depth-3 ring) ----
#pragma unroll
    for (int mt = 0; mt < 4; ++mt)
#pragma unroll
        for (int nt = 0; nt < 4; ++nt) acc[mt][nt] = f32x4{0.f, 0.f, 0.f, 0.f};
    {
        const unsigned short* Bb = hp.W2b + (size_t)(nb0 + l15) * DD + lq * 8;
        bf16x8 b[3][4], a[2][4];
#pragma unroll
        for (int s = 0; s < 3; ++s)
#pragma unroll
            for (int nt = 0; nt < 4; ++nt) b[s][nt] = *(const bf16x8*)(Bb + nt * 16 * DD + s * 32);
#pragma unroll
        for (int mt = 0; mt < 4; ++mt) {
            int row = mt * 16 + l15;
            int ph = (lq & 7) ^ swz(row);
            a[0][mt] = *(const bf16x8*)(hl + row * 256 + ph * 8);
        }
#pragma unroll
        for (int ks = 0; ks < 8; ++ks) {
            int cur = ks & 1, sl = ks % 3;
            if (ks < 7) {
                int ck = (ks + 1) * 4 + lq;
#pragma unroll
                for (int mt = 0; mt < 4; ++mt) {
                    int row = mt * 16 + l15;
                    int ph = (ck & ~7) | ((ck & 7) ^ swz(row));
                    a[cur ^ 1][mt] = *(const bf16x8*)(hl + row * 256 + ph * 8);
                }
            }
#pragma unroll
            for (int nt = 0; nt < 4; ++nt)
#pragma unroll
                for (int mt = 0; mt < 4; ++mt)
                    acc[mt][nt] = __builtin_amdgcn_mfma_f32_16x16x32_bf16(a[cur][mt], b[sl][nt], acc[mt][nt], 0, 0, 0);
            if (ks + 3 < 8) {
#pragma unroll
                for (int nt = 0; nt < 4; ++nt)
                    b[sl][nt] = *(const bf16x8*)(Bb + nt * 16 * DD + (ks + 3) * 32);
            }
        }
    }

    // epilogue 2 in regs: h = gelu(acc + b2)
#pragma unroll
    for (int nt = 0; nt < 4; ++nt) {
        float bias = b2s[nb0 + nt * 16 + l15];
#pragma unroll
        for (int mt = 0; mt < 4; ++mt)
#pragma unroll
            for (int r = 0; r < 4; ++r)
                acc[mt][nt][r] = gelu_f(acc[mt][nt][r] + bias);
    }
    __syncthreads();   // everyone done reading h1

    // write h (bf16) into own column stripe of hl
#pragma unroll
    for (int nt = 0; nt < 4; ++nt) {
        int col = nb0 + nt * 16 + l15;
#pragma unroll
        for (int mt = 0; mt < 4; ++mt)
#pragma unroll
            for (int r = 0; r < 4; ++r) {
                int row = mt * 16 + lq * 4 + r;
                hl[lidx(row, col)] = f2b(acc[mt][nt][r]);
            }
    }

    // ---- projection via MFMA over own 64-col k-slice: h·Wh^T and zhat·Wh^T ----
    f32x4 accP[4], accZ[4];
#pragma unroll
    for (int mt = 0; mt < 4; ++mt) { accP[mt] = f32x4{0.f, 0.f, 0.f, 0.f}; accZ[mt] = f32x4{0.f, 0.f, 0.f, 0.f}; }
    {
        const unsigned short* Wb = hp.Whb + (size_t)l15 * DD + nb0 + lq * 8;
        const unsigned short* zt = zhat + (size_t)n0 * 256;
#pragma unroll
        for (int ks = 0; ks < 2; ++ks) {
            bf16x8 bP = *(const bf16x8*)(Wb + ks * 32);
            int ck = (nb0 >> 3) + ks * 4 + lq;
#pragma unroll
            for (int mt = 0; mt < 4; ++mt) {
                int row = mt * 16 + l15;
                int ph = (ck & ~7) | ((ck & 7) ^ swz(row));
                bf16x8 aP = *(const bf16x8*)(hl + row * 256 + ph * 8);
                bf16x8 aZ = *(const bf16x8*)(zt + row * 256 + ph * 8);
                accP[mt] = __builtin_amdgcn_mfma_f32_16x16x32_bf16(aP, bP, accP[mt], 0, 0, 0);
                accZ[mt] = __builtin_amdgcn_mfma_f32_16x16x32_bf16(aZ, bP, accZ[mt], 0, 0, 0);
            }
        }
    }
    // fold sigma scale per row, write float partials into own stripe
#pragma unroll
    for (int mt = 0; mt < 4; ++mt) {
        int rb = mt * 16 + lq * 4;
#pragma unroll
        for (int r = 0; r < 4; ++r) {
            float pv = accP[mt][r] + rs2s[rb + r] * accZ[mt][r];
            float* pp = (float*)(hl + (rb + r) * 256 + nb0);
            pp[l15] = pv;
        }
    }
    __syncthreads();

    // combine 4 stripes + mu*sumWh + bh + activation/mask + store
    for (int idx = tid; idx < 64 * nc; idx += 256) {
        int row, o;
        if (nc == 1) { row = idx; o = 0; }
        else { row = idx / NCLS; o = idx - row * NCLS; }
        int n = n0 + row;
        if (n < NV) {
            float val = bhs[o] + m2s[row] * swhs[o];
#pragma unroll
            for (int w2 = 0; w2 < 4; ++w2)
                val += ((const float*)(hl + row * 256 + w2 * 64))[o];
            if (head == 0)      opb[n] = 1.f / (1.f + expf(-val));
            else if (head == 2) opl[n] = val;
            else {
                int rng = (int)ranges[n];
                olg[n * NCLS + o] = (o < rng) ? val : -1e9f;
            }
        }
    }
}

extern "C" void kernel_launch(void* const* d_in, const int* in_sizes, int n_in,
                              void* d_out, int out_size, void* d_ws, size_t ws_size,
                              hipStream_t stream) {
    const float* et = (const float*)d_in[0];
    const int*   vb = (const int*)d_in[1];
    const float* aw = (const float*)d_in[2];
    const int*   vt = (const int*)d_in[3];
    const float* z0 = (const float*)d_in[4];
    const float* vf = (const float*)d_in[5];
    const float* Wp = (const float*)d_in[6];
    const float* bp = (const float*)d_in[7];
    const float* fg = (const float*)d_in[8];
    const float* fb = (const float*)d_in[9];
    float* out = (float*)d_out;

    char* ws = (char*)d_ws;
    float* proj          = (float*)ws;                        // 262144 B
    float* b1e           = (float*)(ws + 262144);             // 3072 B (+pad)
    unsigned short* W1e  = (unsigned short*)(ws + 265216);    // 393216 B
    unsigned short* W2b  = (unsigned short*)(ws + 658432);    // 393216 B
    unsigned short* Whb  = (unsigned short*)(ws + 1051648);   // 24576 B
    float* swh           = (float*)(ws + 1076224);            // 192 B (+pad)
    float2* zstat        = (float2*)(ws + 1076480);           // 240128 B
    unsigned short* zhat = (unsigned short*)(ws + 1316608);   // 469*64*512 B -> 16.7 MB

    WP wps[3];
    for (int h = 0; h < 3; ++h) {
        wps[h].W1 = (const float*)d_in[12 + 8 * h];
        wps[h].ng = (const float*)d_in[10 + 8 * h];
        wps[h].nb = (const float*)d_in[11 + 8 * h];
        wps[h].b1 = (const float*)d_in[13 + 8 * h];
        wps[h].W2 = (const float*)d_in[14 + 8 * h];
        wps[h].Wh = (const float*)d_in[16 + 8 * h];
        wps[h].W1e = W1e + h * 65536;
        wps[h].W2b = W2b + h * 65536;
        wps[h].Whb = Whb + h * 4096;
        wps[h].b1e = b1e + h * 256;
        wps[h].swh = swh + h * 16;
        wps[h].nc  = (h == 1) ? NCLS : 1;
    }
    k_prep<<<dim3(256, 4), 256, 0, stream>>>(et, Wp, bp, proj, wps[0], wps[1], wps[2]);

    k_zout<<<7500, 256, 0, stream>>>(proj, vb, aw, z0, fg, fb, vf, vt, out, zhat, zstat);

    HeadP hps[3];
    for (int h = 0; h < 3; ++h) {
        hps[h].W1e = W1e + h * 65536;
        hps[h].W2b = W2b + h * 65536;
        hps[h].Whb = Whb + h * 4096;
        hps[h].b1e = b1e + h * 256;
        hps[h].b2  = (const float*)d_in[15 + 8 * h];
        hps[h].bh  = (const float*)d_in[17 + 8 * h];
        hps[h].swh = swh + h * 16;
        hps[h].nc  = (h == 1) ? NCLS : 1;
    }
    k_heads<<<3 * NT, 256, 0, stream>>>(zhat, zstat, out + ORG,
                                        hps[0], hps[1], hps[2],
                                        out + OPB, out + OLG, out + OPL);
}

// Round 7
// 279.300 us; speedup vs baseline: 1.6675x; 1.0033x over previous
//
#include <hip/hip_runtime.h>
#include <math.h>

#define NV   30000
#define DD   256
#define KK   32
#define NCLS 11
#define NT   469   // row tiles of 64

// output layout (floats)
#define OZ  0
#define OPB 7680000
#define OLG 7710000
#define OPL 8040000
#define OMB 8070000
#define OMS 8100000
#define OML 8130000
#define OOF 8160000
#define ORG 8190000

typedef __bf16 bf16x8 __attribute__((ext_vector_type(8)));
typedef float  f32x4  __attribute__((ext_vector_type(4)));

__device__ __forceinline__ unsigned short f2b(float f) {
    unsigned u = __float_as_uint(f);
    u += 0x7fffu + ((u >> 16) & 1u);
    return (unsigned short)(u >> 16);
}

// tanh-form gelu: x * sigmoid(x*(c0 + c1*x^2)); |err| ~3e-4 << bf16 quantization
__device__ __forceinline__ float gelu_f(float x) {
    float x2 = x * x;
    float m = x * __builtin_fmaf(-0.0713548163f, x2, -1.5957691216f);
    float e = __expf(m);
    return x * __builtin_amdgcn_rcpf(1.0f + e);
}

__device__ __forceinline__ int swz(int row) { return (row + (row >> 3)) & 7; }
__device__ __forceinline__ int lidx(int row, int col) {
    return row * 256 + ((((col) >> 3) ^ swz(row)) << 3) + (col & 7);
}

// ---------------- merged prep: y==0 proj(bf16), y=1..3 per-head weight prep ----------------
struct WP {
    const float *W1, *ng, *nb, *b1, *W2, *Wh;
    unsigned short *W1e, *W2b, *Whb;
    float *b1e, *swh;
    int nc;
};

__global__ void k_prep(const float* __restrict__ et, const float* __restrict__ Wp,
                       const float* __restrict__ bp, unsigned short* __restrict__ projb,
                       WP wa, WP wb, WP wc) {
    __shared__ float es[DD];
    __shared__ float red[4], red2[4];
    if (blockIdx.y == 0) {
        int r = blockIdx.x, c = threadIdx.x;
        es[c] = et[r * DD + c];
        __syncthreads();
        const float4* w4 = (const float4*)(Wp + c * DD);
        float acc = bp[c];
#pragma unroll 16
        for (int d = 0; d < DD / 4; ++d) {
            float4 w = w4[d];
            acc += es[4 * d] * w.x + es[4 * d + 1] * w.y + es[4 * d + 2] * w.z + es[4 * d + 3] * w.w;
        }
        projb[r * DD + c] = f2b(acc);
        return;
    }
    WP wp = (blockIdx.y == 1) ? wa : ((blockIdx.y == 2) ? wb : wc);
    int j = blockIdx.x, d = threadIdx.x;
    float v1 = wp.W1[j * DD + d];
    wp.W1e[j * DD + d] = f2b(v1 * wp.ng[d]);
    wp.W2b[j * DD + d] = f2b(wp.W2[j * DD + d]);
    float p2 = 0.f;
    if (j < 16) {
        p2 = (j < wp.nc) ? wp.Wh[j * DD + d] : 0.f;
        wp.Whb[j * DD + d] = f2b(p2);
    }
    float p = v1 * wp.nb[d];
#pragma unroll
    for (int m = 1; m < 64; m <<= 1) { p += __shfl_xor(p, m); p2 += __shfl_xor(p2, m); }
    if ((d & 63) == 0) { red[d >> 6] = p; red2[d >> 6] = p2; }
    __syncthreads();
    if (d == 0) {
        wp.b1e[j] = wp.b1[j] + red[0] + red[1] + red[2] + red[3];
        if (j < 16) wp.swh[j] = red2[0] + red2[1] + red2[2] + red2[3];
    }
}

// ---- z_out = LN(einsum+z0); zhat bf16 (pre-swizzled tiles); zstat=(sigma,mu); masks ----
__global__ __launch_bounds__(256)
void k_zout(const unsigned short* __restrict__ projb, const int* __restrict__ vb,
            const float* __restrict__ aw, const float* __restrict__ z0,
            const float* __restrict__ g, const float* __restrict__ b,
            const float* __restrict__ vf, const int* __restrict__ vt,
            float* __restrict__ out, unsigned short* __restrict__ zhat,
            float2* __restrict__ zstat) {
    int wv = threadIdx.x >> 6, lane = threadIdx.x & 63;
    int n = blockIdx.x * 4 + wv;
    if (n >= NV) return;
    int bidx = vb[n];
    float awv = aw[n * KK + (lane & 31)];
    const ushort4* pr = (const ushort4*)(projb + (size_t)bidx * KK * DD);
    float4 acc = ((const float4*)(z0 + (size_t)n * DD))[lane];
#pragma unroll 8
    for (int k = 0; k < KK; ++k) {
        float a = __shfl(awv, k);
        ushort4 pu = pr[k * 64 + lane];
        acc.x += a * __uint_as_float((unsigned)pu.x << 16);
        acc.y += a * __uint_as_float((unsigned)pu.y << 16);
        acc.z += a * __uint_as_float((unsigned)pu.z << 16);
        acc.w += a * __uint_as_float((unsigned)pu.w << 16);
    }
    // LN1
    float s = acc.x + acc.y + acc.z + acc.w;
    float q = acc.x * acc.x + acc.y * acc.y + acc.z * acc.z + acc.w * acc.w;
#pragma unroll
    for (int m = 1; m < 64; m <<= 1) { s += __shfl_xor(s, m); q += __shfl_xor(q, m); }
    float mean = s * (1.f / DD);
    float var  = q * (1.f / DD) - mean * mean;
    float rs   = rsqrtf(var + 1e-5f);
    float4 g4 = ((const float4*)g)[lane], b4 = ((const float4*)b)[lane];
    float4 z;
    z.x = (acc.x - mean) * rs * g4.x + b4.x;
    z.y = (acc.y - mean) * rs * g4.y + b4.y;
    z.z = (acc.z - mean) * rs * g4.z + b4.z;
    z.w = (acc.w - mean) * rs * g4.w + b4.w;
    ((float4*)(out + OZ + (size_t)n * DD))[lane] = z;
    // LN2 (no affine) -> zhat bf16, pre-swizzled tile layout
    float s2 = z.x + z.y + z.z + z.w;
    float q2 = z.x * z.x + z.y * z.y + z.z * z.z + z.w * z.w;
#pragma unroll
    for (int m = 1; m < 64; m <<= 1) { s2 += __shfl_xor(s2, m); q2 += __shfl_xor(q2, m); }
    float m2 = s2 * (1.f / DD);
    float v2 = q2 * (1.f / DD) - m2 * m2;
    float r2 = rsqrtf(v2 + 1e-5f);
    ushort4 zh;
    zh.x = f2b((z.x - m2) * r2); zh.y = f2b((z.y - m2) * r2);
    zh.z = f2b((z.z - m2) * r2); zh.w = f2b((z.w - m2) * r2);
    int rl = n & 63;
    int c = lane >> 1;
    int pc = (c & ~7) | ((c & 7) ^ swz(rl));
    *(ushort4*)(zhat + (size_t)(n & ~63) * 256 + rl * 256 + pc * 8 + (lane & 1) * 4) = zh;
    if (lane == 0) {
        zstat[n] = make_float2((v2 + 1e-5f) * r2, m2);
        float lb = vf[n * 23 + 21], ub = vf[n * 23 + 22];
        int t = vt[n];
        bool is_int = (t == 2);
        bool finite = (fabsf(lb) < 1e18f) && (fabsf(ub) < 1e18f);
        bool small_ = is_int && finite && (ub - lb <= 10.0f);
        float off = floorf(lb);
        float rngf = ceilf(ub) - off + 1.0f;
        rngf = fminf(fmaxf(rngf, 1.0f), (float)NCLS);
        out[OMB + n] = (t == 1) ? 1.0f : 0.0f;
        out[OMS + n] = small_ ? 1.0f : 0.0f;
        out[OML + n] = (is_int && !small_) ? 1.0f : 0.0f;
        out[OOF + n] = off;
        out[ORG + n] = (float)((int)rngf);
    }
}

// ---------------- per-head MLP kernel ----------------
struct HeadP {
    const unsigned short *W1e, *W2b, *Whb;
    const float *b1e, *b2, *bh, *swh;
    int nc;
};

__global__ __launch_bounds__(256, 4)
void k_heads(const unsigned short* __restrict__ zhat, const float2* __restrict__ zstat,
             const float* __restrict__ ranges,
             HeadP h0, HeadP h1p, HeadP h2p,
             float* __restrict__ opb, float* __restrict__ olg, float* __restrict__ opl) {
    __shared__ unsigned short hl[64 * 256];   // 32 KB: zhat tile -> h1 -> h -> partials
    __shared__ float b1s[DD], b2s[DD];
    __shared__ float rs2s[64], m2s[64];
    __shared__ float swhs[16], bhs[16];

    int head = blockIdx.x / NT;
    int tile = blockIdx.x % NT;
    HeadP hp = (head == 0) ? h0 : ((head == 1) ? h1p : h2p);
    int nc = hp.nc;
    int n0 = tile * 64;
    int tid = threadIdx.x;

    // stage zhat tile (pre-swizzled -> straight copy) + biases + stats
    {
        const uint4* src = (const uint4*)(zhat + (size_t)n0 * 256);
        uint4* dst = (uint4*)hl;
#pragma unroll
        for (int j = 0; j < 8; ++j) dst[tid + j * 256] = src[tid + j * 256];
    }
    b1s[tid] = hp.b1e[tid];
    b2s[tid] = hp.b2[tid];
    if (tid < 64) {
        int n = n0 + tid;
        float2 st = (n < NV) ? zstat[n] : make_float2(0.f, 0.f);
        rs2s[tid] = st.x; m2s[tid] = st.y;
    } else if (tid < 80) {
        swhs[tid - 64] = hp.swh[tid - 64];
    } else if (tid < 96) {
        int o = tid - 80;
        bhs[o] = (o < nc) ? hp.bh[o] : 0.f;
    }

    int lane = tid & 63, wv = tid >> 6;
    int l15 = lane & 15, lq = lane >> 4;
    int nb0 = wv * 64;

    f32x4 acc[4][4];
#pragma unroll
    for (int mt = 0; mt < 4; ++mt)
#pragma unroll
        for (int nt = 0; nt < 4; ++nt) acc[mt][nt] = f32x4{0.f, 0.f, 0.f, 0.f};

    __syncthreads();

    // ---- GEMM1: zhat(LDS) @ W1e.T(global, b double-buffer; a single-buffer) ----
    {
        const unsigned short* Bb = hp.W1e + (size_t)(nb0 + l15) * DD + lq * 8;
        bf16x8 b[2][4], a[4];
#pragma unroll
        for (int nt = 0; nt < 4; ++nt) b[0][nt] = *(const bf16x8*)(Bb + nt * 16 * DD);
#pragma unroll
        for (int ks = 0; ks < 8; ++ks) {
            int cur = ks & 1;
            if (ks < 7) {
#pragma unroll
                for (int nt = 0; nt < 4; ++nt)
                    b[cur ^ 1][nt] = *(const bf16x8*)(Bb + nt * 16 * DD + (ks + 1) * 32);
            }
            int ck = ks * 4 + lq;
#pragma unroll
            for (int mt = 0; mt < 4; ++mt) {
                int row = mt * 16 + l15;
                int ph = (ck & ~7) | ((ck & 7) ^ swz(row));
                a[mt] = *(const bf16x8*)(hl + row * 256 + ph * 8);
            }
#pragma unroll
            for (int nt = 0; nt < 4; ++nt)
#pragma unroll
                for (int mt = 0; mt < 4; ++mt)
                    acc[mt][nt] = __builtin_amdgcn_mfma_f32_16x16x32_bf16(a[mt], b[cur][nt], acc[mt][nt], 0, 0, 0);
        }
    }
    __syncthreads();   // all waves done reading zhat tile

    // epilogue 1: +b1e, gelu -> hl (bf16, swizzled)
#pragma unroll
    for (int nt = 0; nt < 4; ++nt) {
        int col = nb0 + nt * 16 + l15;
        float bias = b1s[col];
#pragma unroll
        for (int mt = 0; mt < 4; ++mt)
#pragma unroll
            for (int r = 0; r < 4; ++r) {
                int row = mt * 16 + lq * 4 + r;
                hl[lidx(row, col)] = f2b(gelu_f(acc[mt][nt][r] + bias));
            }
    }
    __syncthreads();

    // ---- GEMM2: h1(LDS) @ W2.T(global) ----
#pragma unroll
    for (int mt = 0; mt < 4; ++mt)
#pragma unroll
        for (int nt = 0; nt < 4; ++nt) acc[mt][nt] = f32x4{0.f, 0.f, 0.f, 0.f};
    {
        const unsigned short* Bb = hp.W2b + (size_t)(nb0 + l15) * DD + lq * 8;
        bf16x8 b[2][4], a[4];
#pragma unroll
        for (int nt = 0; nt < 4; ++nt) b[0][nt] = *(const bf16x8*)(Bb + nt * 16 * DD);
#pragma unroll
        for (int ks = 0; ks < 8; ++ks) {
            int cur = ks & 1;
            if (ks < 7) {
#pragma unroll
                for (int nt = 0; nt < 4; ++nt)
                    b[cur ^ 1][nt] = *(const bf16x8*)(Bb + nt * 16 * DD + (ks + 1) * 32);
            }
            int ck = ks * 4 + lq;
#pragma unroll
            for (int mt = 0; mt < 4; ++mt) {
                int row = mt * 16 + l15;
                int ph = (ck & ~7) | ((ck & 7) ^ swz(row));
                a[mt] = *(const bf16x8*)(hl + row * 256 + ph * 8);
            }
#pragma unroll
            for (int nt = 0; nt < 4; ++nt)
#pragma unroll
                for (int mt = 0; mt < 4; ++mt)
                    acc[mt][nt] = __builtin_amdgcn_mfma_f32_16x16x32_bf16(a[mt], b[cur][nt], acc[mt][nt], 0, 0, 0);
        }
    }

    // epilogue 2 in regs: h = gelu(acc + b2)
#pragma unroll
    for (int nt = 0; nt < 4; ++nt) {
        float bias = b2s[nb0 + nt * 16 + l15];
#pragma unroll
        for (int mt = 0; mt < 4; ++mt)
#pragma unroll
            for (int r = 0; r < 4; ++r)
                acc[mt][nt][r] = gelu_f(acc[mt][nt][r] + bias);
    }
    __syncthreads();   // everyone done reading h1

    // write h (bf16) into own column stripe of hl
#pragma unroll
    for (int nt = 0; nt < 4; ++nt) {
        int col = nb0 + nt * 16 + l15;
#pragma unroll
        for (int mt = 0; mt < 4; ++mt)
#pragma unroll
            for (int r = 0; r < 4; ++r) {
                int row = mt * 16 + lq * 4 + r;
                hl[lidx(row, col)] = f2b(acc[mt][nt][r]);
            }
    }

    // ---- projection via MFMA over own 64-col k-slice: h·Wh^T and zhat·Wh^T ----
    f32x4 accP[4], accZ[4];
#pragma unroll
    for (int mt = 0; mt < 4; ++mt) { accP[mt] = f32x4{0.f, 0.f, 0.f, 0.f}; accZ[mt] = f32x4{0.f, 0.f, 0.f, 0.f}; }
    {
        const unsigned short* Wb = hp.Whb + (size_t)l15 * DD + nb0 + lq * 8;
        const unsigned short* zt = zhat + (size_t)n0 * 256;
#pragma unroll
        for (int ks = 0; ks < 2; ++ks) {
            bf16x8 bP = *(const bf16x8*)(Wb + ks * 32);
            int ck = (nb0 >> 3) + ks * 4 + lq;
#pragma unroll
            for (int mt = 0; mt < 4; ++mt) {
                int row = mt * 16 + l15;
                int ph = (ck & ~7) | ((ck & 7) ^ swz(row));
                bf16x8 aP = *(const bf16x8*)(hl + row * 256 + ph * 8);
                bf16x8 aZ = *(const bf16x8*)(zt + row * 256 + ph * 8);
                accP[mt] = __builtin_amdgcn_mfma_f32_16x16x32_bf16(aP, bP, accP[mt], 0, 0, 0);
                accZ[mt] = __builtin_amdgcn_mfma_f32_16x16x32_bf16(aZ, bP, accZ[mt], 0, 0, 0);
            }
        }
    }
    // fold sigma scale per row, write float partials into own stripe
#pragma unroll
    for (int mt = 0; mt < 4; ++mt) {
        int rb = mt * 16 + lq * 4;
#pragma unroll
        for (int r = 0; r < 4; ++r) {
            float pv = accP[mt][r] + rs2s[rb + r] * accZ[mt][r];
            float* pp = (float*)(hl + (rb + r) * 256 + nb0);
            pp[l15] = pv;
        }
    }
    __syncthreads();

    // combine 4 stripes + mu*sumWh + bh + activation/mask + store
    for (int idx = tid; idx < 64 * nc; idx += 256) {
        int row, o;
        if (nc == 1) { row = idx; o = 0; }
        else { row = idx / NCLS; o = idx - row * NCLS; }
        int n = n0 + row;
        if (n < NV) {
            float val = bhs[o] + m2s[row] * swhs[o];
#pragma unroll
            for (int w2 = 0; w2 < 4; ++w2)
                val += ((const float*)(hl + row * 256 + w2 * 64))[o];
            if (head == 0)      opb[n] = __builtin_amdgcn_rcpf(1.f + __expf(-val));
            else if (head == 2) opl[n] = val;
            else {
                int rng = (int)ranges[n];
                olg[n * NCLS + o] = (o < rng) ? val : -1e9f;
            }
        }
    }
}

extern "C" void kernel_launch(void* const* d_in, const int* in_sizes, int n_in,
                              void* d_out, int out_size, void* d_ws, size_t ws_size,
                              hipStream_t stream) {
    const float* et = (const float*)d_in[0];
    const int*   vb = (const int*)d_in[1];
    const float* aw = (const float*)d_in[2];
    const int*   vt = (const int*)d_in[3];
    const float* z0 = (const float*)d_in[4];
    const float* vf = (const float*)d_in[5];
    const float* Wp = (const float*)d_in[6];
    const float* bp = (const float*)d_in[7];
    const float* fg = (const float*)d_in[8];
    const float* fb = (const float*)d_in[9];
    float* out = (float*)d_out;

    char* ws = (char*)d_ws;
    unsigned short* projb = (unsigned short*)ws;              // 131072 B
    float* b1e           = (float*)(ws + 131072);             // 3072 B (+pad)
    unsigned short* W1e  = (unsigned short*)(ws + 134144);    // 393216 B
    unsigned short* W2b  = (unsigned short*)(ws + 527360);    // 393216 B
    unsigned short* Whb  = (unsigned short*)(ws + 920576);    // 24576 B
    float* swh           = (float*)(ws + 945152);             // 192 B (+pad)
    float2* zstat        = (float2*)(ws + 945408);            // 240128 B
    unsigned short* zhat = (unsigned short*)(ws + 1185536);   // 469*64*512 B -> ~16.6 MB

    WP wps[3];
    for (int h = 0; h < 3; ++h) {
        wps[h].W1 = (const float*)d_in[12 + 8 * h];
        wps[h].ng = (const float*)d_in[10 + 8 * h];
        wps[h].nb = (const float*)d_in[11 + 8 * h];
        wps[h].b1 = (const float*)d_in[13 + 8 * h];
        wps[h].W2 = (const float*)d_in[14 + 8 * h];
        wps[h].Wh = (const float*)d_in[16 + 8 * h];
        wps[h].W1e = W1e + h * 65536;
        wps[h].W2b = W2b + h * 65536;
        wps[h].Whb = Whb + h * 4096;
        wps[h].b1e = b1e + h * 256;
        wps[h].swh = swh + h * 16;
        wps[h].nc  = (h == 1) ? NCLS : 1;
    }
    k_prep<<<dim3(256, 4), 256, 0, stream>>>(et, Wp, bp, projb, wps[0], wps[1], wps[2]);

    k_zout<<<7500, 256, 0, stream>>>(projb, vb, aw, z0, fg, fb, vf, vt, out, zhat, zstat);

    HeadP hps[3];
    for (int h = 0; h < 3; ++h) {
        hps[h].W1e = W1e + h * 65536;
        hps[h].W2b = W2b + h * 65536;
        hps[h].Whb = Whb + h * 4096;
        hps[h].b1e = b1e + h * 256;
        hps[h].b2  = (const float*)d_in[15 + 8 * h];
        hps[h].bh  = (const float*)d_in[17 + 8 * h];
        hps[h].swh = swh + h * 16;
        hps[h].nc  = (h == 1) ? NCLS : 1;
    }
    k_heads<<<3 * NT, 256, 0, stream>>>(zhat, zstat, out + ORG,
                                        hps[0], hps[1], hps[2],
                                        out + OPB, out + OLG, out + OPL);
}

// Round 8
// 250.204 us; speedup vs baseline: 1.8614x; 1.1163x over previous
//
#include <hip/hip_runtime.h>
#include <math.h>

#define NV   30000
#define DD   256
#define KK   32
#define NCLS 11
#define NT   469   // row tiles of 64

// output layout (floats)
#define OZ  0
#define OPB 7680000
#define OLG 7710000
#define OPL 8040000
#define OMB 8070000
#define OMS 8100000
#define OML 8130000
#define OOF 8160000
#define ORG 8190000

typedef __bf16 bf16x8 __attribute__((ext_vector_type(8)));
typedef float  f32x4  __attribute__((ext_vector_type(4)));

__device__ __forceinline__ unsigned short f2b(float f) {
    unsigned u = __float_as_uint(f);
    u += 0x7fffu + ((u >> 16) & 1u);
    return (unsigned short)(u >> 16);
}

// tanh-form gelu: x * sigmoid(x*(c0 + c1*x^2)); |err| ~3e-4 << bf16 quantization
__device__ __forceinline__ float gelu_f(float x) {
    float x2 = x * x;
    float m = x * __builtin_fmaf(-0.0713548163f, x2, -1.5957691216f);
    float e = __expf(m);
    return x * __builtin_amdgcn_rcpf(1.0f + e);
}

__device__ __forceinline__ int swz(int row) { return (row + (row >> 3)) & 7; }
__device__ __forceinline__ int lidx(int row, int col) {
    return row * 256 + ((((col) >> 3) ^ swz(row)) << 3) + (col & 7);
}

// ------ merged prep: y==0 proj(bf16), y=1..3 weight prep, y==4 masks ------
struct WP {
    const float *W1, *ng, *nb, *b1, *W2, *Wh;
    unsigned short *W1e, *W2b, *Whb;
    float *b1e, *swh;
    int nc;
};

__global__ void k_prep(const float* __restrict__ et, const float* __restrict__ Wp,
                       const float* __restrict__ bp, unsigned short* __restrict__ projb,
                       const float* __restrict__ vf, const int* __restrict__ vt,
                       float* __restrict__ out,
                       WP wa, WP wb, WP wc) {
    __shared__ float es[DD];
    __shared__ float red[4], red2[4];
    if (blockIdx.y == 0) {
        int r = blockIdx.x, c = threadIdx.x;
        es[c] = et[r * DD + c];
        __syncthreads();
        const float4* w4 = (const float4*)(Wp + c * DD);
        float acc = bp[c];
#pragma unroll 16
        for (int d = 0; d < DD / 4; ++d) {
            float4 w = w4[d];
            acc += es[4 * d] * w.x + es[4 * d + 1] * w.y + es[4 * d + 2] * w.z + es[4 * d + 3] * w.w;
        }
        projb[r * DD + c] = f2b(acc);
        return;
    }
    if (blockIdx.y == 4) {
        int n = blockIdx.x * 256 + threadIdx.x;
        if (n < NV) {
            float lb = vf[n * 23 + 21], ub = vf[n * 23 + 22];
            int t = vt[n];
            bool is_int = (t == 2);
            bool finite = (fabsf(lb) < 1e18f) && (fabsf(ub) < 1e18f);
            bool small_ = is_int && finite && (ub - lb <= 10.0f);
            float off = floorf(lb);
            float rngf = ceilf(ub) - off + 1.0f;
            rngf = fminf(fmaxf(rngf, 1.0f), (float)NCLS);
            out[OMB + n] = (t == 1) ? 1.0f : 0.0f;
            out[OMS + n] = small_ ? 1.0f : 0.0f;
            out[OML + n] = (is_int && !small_) ? 1.0f : 0.0f;
            out[OOF + n] = off;
            out[ORG + n] = (float)((int)rngf);
        }
        return;
    }
    WP wp = (blockIdx.y == 1) ? wa : ((blockIdx.y == 2) ? wb : wc);
    int j = blockIdx.x, d = threadIdx.x;
    float v1 = wp.W1[j * DD + d];
    wp.W1e[j * DD + d] = f2b(v1 * wp.ng[d]);
    wp.W2b[j * DD + d] = f2b(wp.W2[j * DD + d]);
    float p2 = 0.f;
    if (j < 16) {
        p2 = (j < wp.nc) ? wp.Wh[j * DD + d] : 0.f;
        wp.Whb[j * DD + d] = f2b(p2);
    }
    float p = v1 * wp.nb[d];
#pragma unroll
    for (int m = 1; m < 64; m <<= 1) { p += __shfl_xor(p, m); p2 += __shfl_xor(p2, m); }
    if ((d & 63) == 0) { red[d >> 6] = p; red2[d >> 6] = p2; }
    __syncthreads();
    if (d == 0) {
        wp.b1e[j] = wp.b1[j] + red[0] + red[1] + red[2] + red[3];
        if (j < 16) wp.swh[j] = red2[0] + red2[1] + red2[2] + red2[3];
    }
}

// ---- z_out = LN(einsum+z0); zhat bf16 pre-swizzled; zstat; 2 rows per wave ----
__global__ __launch_bounds__(256)
void k_zout(const unsigned short* __restrict__ projb, const int* __restrict__ vb,
            const float* __restrict__ aw, const float* __restrict__ z0,
            const float* __restrict__ g, const float* __restrict__ b,
            float* __restrict__ out, unsigned short* __restrict__ zhat,
            float2* __restrict__ zstat) {
    int wv = threadIdx.x >> 6, lane = threadIdx.x & 63;
    int n0r = blockIdx.x * 8 + wv * 2;
    if (n0r >= NV) return;
    bool ok1 = (n0r + 1) < NV;
    int b0 = vb[n0r];
    int b1i = ok1 ? vb[n0r + 1] : b0;
    float aw0 = aw[(size_t)n0r * KK + (lane & 31)];
    float aw1 = ok1 ? aw[(size_t)(n0r + 1) * KK + (lane & 31)] : 0.f;
    const ushort4* pr0 = (const ushort4*)(projb + (size_t)b0 * KK * DD);
    const ushort4* pr1 = (const ushort4*)(projb + (size_t)b1i * KK * DD);
    float4 acc0 = ((const float4*)(z0 + (size_t)n0r * DD))[lane];
    float4 acc1 = ok1 ? ((const float4*)(z0 + (size_t)(n0r + 1) * DD))[lane]
                      : make_float4(0.f, 0.f, 0.f, 0.f);
#pragma unroll 4
    for (int k = 0; k < KK; ++k) {
        float a0 = __shfl(aw0, k), a1 = __shfl(aw1, k);
        ushort4 p0 = pr0[k * 64 + lane];
        ushort4 p1 = pr1[k * 64 + lane];
        acc0.x += a0 * __uint_as_float((unsigned)p0.x << 16);
        acc0.y += a0 * __uint_as_float((unsigned)p0.y << 16);
        acc0.z += a0 * __uint_as_float((unsigned)p0.z << 16);
        acc0.w += a0 * __uint_as_float((unsigned)p0.w << 16);
        acc1.x += a1 * __uint_as_float((unsigned)p1.x << 16);
        acc1.y += a1 * __uint_as_float((unsigned)p1.y << 16);
        acc1.z += a1 * __uint_as_float((unsigned)p1.z << 16);
        acc1.w += a1 * __uint_as_float((unsigned)p1.w << 16);
    }
    // LN1 (both rows, interleaved butterflies)
    float s0 = acc0.x + acc0.y + acc0.z + acc0.w;
    float q0 = acc0.x * acc0.x + acc0.y * acc0.y + acc0.z * acc0.z + acc0.w * acc0.w;
    float s1 = acc1.x + acc1.y + acc1.z + acc1.w;
    float q1 = acc1.x * acc1.x + acc1.y * acc1.y + acc1.z * acc1.z + acc1.w * acc1.w;
#pragma unroll
    for (int m = 1; m < 64; m <<= 1) {
        s0 += __shfl_xor(s0, m); q0 += __shfl_xor(q0, m);
        s1 += __shfl_xor(s1, m); q1 += __shfl_xor(q1, m);
    }
    float4 g4 = ((const float4*)g)[lane], b4 = ((const float4*)b)[lane];
#pragma unroll
    for (int rr = 0; rr < 2; ++rr) {
        int n = n0r + rr;
        if (rr && !ok1) break;
        float4 acc = rr ? acc1 : acc0;
        float s = rr ? s1 : s0, q = rr ? q1 : q0;
        float mean = s * (1.f / DD);
        float var  = q * (1.f / DD) - mean * mean;
        float rs   = rsqrtf(var + 1e-5f);
        float4 z;
        z.x = (acc.x - mean) * rs * g4.x + b4.x;
        z.y = (acc.y - mean) * rs * g4.y + b4.y;
        z.z = (acc.z - mean) * rs * g4.z + b4.z;
        z.w = (acc.w - mean) * rs * g4.w + b4.w;
        ((float4*)(out + OZ + (size_t)n * DD))[lane] = z;
        float s2 = z.x + z.y + z.z + z.w;
        float q2 = z.x * z.x + z.y * z.y + z.z * z.z + z.w * z.w;
#pragma unroll
        for (int m = 1; m < 64; m <<= 1) { s2 += __shfl_xor(s2, m); q2 += __shfl_xor(q2, m); }
        float m2 = s2 * (1.f / DD);
        float v2 = q2 * (1.f / DD) - m2 * m2;
        float r2 = rsqrtf(v2 + 1e-5f);
        ushort4 zh;
        zh.x = f2b((z.x - m2) * r2); zh.y = f2b((z.y - m2) * r2);
        zh.z = f2b((z.z - m2) * r2); zh.w = f2b((z.w - m2) * r2);
        int rl = n & 63;
        int c = lane >> 1;
        int pc = (c & ~7) | ((c & 7) ^ swz(rl));
        *(ushort4*)(zhat + (size_t)(n & ~63) * 256 + rl * 256 + pc * 8 + (lane & 1) * 4) = zh;
        if (lane == 0) zstat[n] = make_float2((v2 + 1e-5f) * r2, m2);
    }
}

// ---------------- per-head MLP kernel: 512 thr, 8 waves x (64x32) ----------------
struct HeadP {
    const unsigned short *W1e, *W2b, *Whb;
    const float *b1e, *b2, *bh, *swh;
    int nc;
};

__global__ __launch_bounds__(512, 4)
void k_heads(const unsigned short* __restrict__ zhat, const float2* __restrict__ zstat,
             const float* __restrict__ ranges,
             HeadP h0, HeadP h1p, HeadP h2p,
             float* __restrict__ opb, float* __restrict__ olg, float* __restrict__ opl) {
    __shared__ unsigned short hl[64 * 256];   // 32 KB: zhat tile -> h1 -> h -> partials
    __shared__ float b1s[DD], b2s[DD];
    __shared__ float rs2s[64], m2s[64];
    __shared__ float swhs[16], bhs[16];

    int head = blockIdx.x / NT;
    int tile = blockIdx.x % NT;
    HeadP hp = (head == 0) ? h0 : ((head == 1) ? h1p : h2p);
    int nc = hp.nc;
    int n0 = tile * 64;
    int tid = threadIdx.x;

    // stage zhat tile (pre-swizzled -> straight copy) + biases + stats
    {
        const uint4* src = (const uint4*)(zhat + (size_t)n0 * 256);
        uint4* dst = (uint4*)hl;
#pragma unroll
        for (int j = 0; j < 4; ++j) dst[tid + j * 512] = src[tid + j * 512];
    }
    if (tid < 256) b1s[tid] = hp.b1e[tid];
    else           b2s[tid - 256] = hp.b2[tid - 256];
    if (tid < 64) {
        int n = n0 + tid;
        float2 st = (n < NV) ? zstat[n] : make_float2(0.f, 0.f);
        rs2s[tid] = st.x; m2s[tid] = st.y;
    } else if (tid < 80) {
        swhs[tid - 64] = hp.swh[tid - 64];
    } else if (tid < 96) {
        int o = tid - 80;
        bhs[o] = (o < nc) ? hp.bh[o] : 0.f;
    }

    int lane = tid & 63, wv = tid >> 6;      // wv 0..7
    int l15 = lane & 15, lq = lane >> 4;
    int nb0 = wv * 32;

    f32x4 acc[4][2];
#pragma unroll
    for (int mt = 0; mt < 4; ++mt)
#pragma unroll
        for (int nt = 0; nt < 2; ++nt) acc[mt][nt] = f32x4{0.f, 0.f, 0.f, 0.f};

    __syncthreads();

    // ---- GEMM1: zhat(LDS) @ W1e.T(global, b double-buffer) ----
    {
        const unsigned short* Bb = hp.W1e + (size_t)(nb0 + l15) * DD + lq * 8;
        bf16x8 b[2][2], a[4];
#pragma unroll
        for (int nt = 0; nt < 2; ++nt) b[0][nt] = *(const bf16x8*)(Bb + nt * 16 * DD);
#pragma unroll
        for (int ks = 0; ks < 8; ++ks) {
            int cur = ks & 1;
            if (ks < 7) {
#pragma unroll
                for (int nt = 0; nt < 2; ++nt)
                    b[cur ^ 1][nt] = *(const bf16x8*)(Bb + nt * 16 * DD + (ks + 1) * 32);
            }
            int ck = ks * 4 + lq;
#pragma unroll
            for (int mt = 0; mt < 4; ++mt) {
                int row = mt * 16 + l15;
                int ph = (ck & ~7) | ((ck & 7) ^ swz(row));
                a[mt] = *(const bf16x8*)(hl + row * 256 + ph * 8);
            }
#pragma unroll
            for (int nt = 0; nt < 2; ++nt)
#pragma unroll
                for (int mt = 0; mt < 4; ++mt)
                    acc[mt][nt] = __builtin_amdgcn_mfma_f32_16x16x32_bf16(a[mt], b[cur][nt], acc[mt][nt], 0, 0, 0);
        }
    }
    __syncthreads();   // all waves done reading zhat tile

    // epilogue 1: +b1e, gelu -> hl (bf16, swizzled), own 32-col stripe
#pragma unroll
    for (int nt = 0; nt < 2; ++nt) {
        int col = nb0 + nt * 16 + l15;
        float bias = b1s[col];
#pragma unroll
        for (int mt = 0; mt < 4; ++mt)
#pragma unroll
            for (int r = 0; r < 4; ++r) {
                int row = mt * 16 + lq * 4 + r;
                hl[lidx(row, col)] = f2b(gelu_f(acc[mt][nt][r] + bias));
            }
    }
    __syncthreads();

    // ---- GEMM2: h1(LDS) @ W2.T(global) ----
#pragma unroll
    for (int mt = 0; mt < 4; ++mt)
#pragma unroll
        for (int nt = 0; nt < 2; ++nt) acc[mt][nt] = f32x4{0.f, 0.f, 0.f, 0.f};
    {
        const unsigned short* Bb = hp.W2b + (size_t)(nb0 + l15) * DD + lq * 8;
        bf16x8 b[2][2], a[4];
#pragma unroll
        for (int nt = 0; nt < 2; ++nt) b[0][nt] = *(const bf16x8*)(Bb + nt * 16 * DD);
#pragma unroll
        for (int ks = 0; ks < 8; ++ks) {
            int cur = ks & 1;
            if (ks < 7) {
#pragma unroll
                for (int nt = 0; nt < 2; ++nt)
                    b[cur ^ 1][nt] = *(const bf16x8*)(Bb + nt * 16 * DD + (ks + 1) * 32);
            }
            int ck = ks * 4 + lq;
#pragma unroll
            for (int mt = 0; mt < 4; ++mt) {
                int row = mt * 16 + l15;
                int ph = (ck & ~7) | ((ck & 7) ^ swz(row));
                a[mt] = *(const bf16x8*)(hl + row * 256 + ph * 8);
            }
#pragma unroll
            for (int nt = 0; nt < 2; ++nt)
#pragma unroll
                for (int mt = 0; mt < 4; ++mt)
                    acc[mt][nt] = __builtin_amdgcn_mfma_f32_16x16x32_bf16(a[mt], b[cur][nt], acc[mt][nt], 0, 0, 0);
        }
    }

    // epilogue 2 in regs: h = gelu(acc + b2)
#pragma unroll
    for (int nt = 0; nt < 2; ++nt) {
        float bias = b2s[nb0 + nt * 16 + l15];
#pragma unroll
        for (int mt = 0; mt < 4; ++mt)
#pragma unroll
            for (int r = 0; r < 4; ++r)
                acc[mt][nt][r] = gelu_f(acc[mt][nt][r] + bias);
    }
    __syncthreads();   // everyone done reading h1

    // write h (bf16) into own 32-col stripe of hl
#pragma unroll
    for (int nt = 0; nt < 2; ++nt) {
        int col = nb0 + nt * 16 + l15;
#pragma unroll
        for (int mt = 0; mt < 4; ++mt)
#pragma unroll
            for (int r = 0; r < 4; ++r) {
                int row = mt * 16 + lq * 4 + r;
                hl[lidx(row, col)] = f2b(acc[mt][nt][r]);
            }
    }

    // ---- projection via MFMA over own 32-col k-slice: h·Wh^T and zhat·Wh^T ----
    f32x4 accP[4], accZ[4];
#pragma unroll
    for (int mt = 0; mt < 4; ++mt) { accP[mt] = f32x4{0.f, 0.f, 0.f, 0.f}; accZ[mt] = f32x4{0.f, 0.f, 0.f, 0.f}; }
    {
        const unsigned short* Wb = hp.Whb + (size_t)l15 * DD + nb0 + lq * 8;
        const unsigned short* zt = zhat + (size_t)n0 * 256;
        bf16x8 bP = *(const bf16x8*)(Wb);
        int ck = (nb0 >> 3) + lq;
#pragma unroll
        for (int mt = 0; mt < 4; ++mt) {
            int row = mt * 16 + l15;
            int ph = (ck & ~7) | ((ck & 7) ^ swz(row));
            bf16x8 aP = *(const bf16x8*)(hl + row * 256 + ph * 8);
            bf16x8 aZ = *(const bf16x8*)(zt + row * 256 + ph * 8);
            accP[mt] = __builtin_amdgcn_mfma_f32_16x16x32_bf16(aP, bP, accP[mt], 0, 0, 0);
            accZ[mt] = __builtin_amdgcn_mfma_f32_16x16x32_bf16(aZ, bP, accZ[mt], 0, 0, 0);
        }
    }
    __syncthreads();   // proj A-reads (span neighbor stripes via swizzle) done before partial writes

    // fold sigma per row, write float partials into own 16-float stripe
#pragma unroll
    for (int mt = 0; mt < 4; ++mt) {
        int rb = mt * 16 + lq * 4;
#pragma unroll
        for (int r = 0; r < 4; ++r) {
            float pv = accP[mt][r] + rs2s[rb + r] * accZ[mt][r];
            float* pp = (float*)(hl + (rb + r) * 256 + nb0);
            pp[l15] = pv;
        }
    }
    __syncthreads();

    // combine 8 stripes + mu*sumWh + bh + activation/mask + store
    for (int idx = tid; idx < 64 * nc; idx += 512) {
        int row, o;
        if (nc == 1) { row = idx; o = 0; }
        else { row = idx / NCLS; o = idx - row * NCLS; }
        int n = n0 + row;
        if (n < NV) {
            float val = bhs[o] + m2s[row] * swhs[o];
#pragma unroll
            for (int w2 = 0; w2 < 8; ++w2)
                val += ((const float*)(hl + row * 256 + w2 * 32))[o];
            if (head == 0)      opb[n] = __builtin_amdgcn_rcpf(1.f + __expf(-val));
            else if (head == 2) opl[n] = val;
            else {
                int rng = (int)ranges[n];
                olg[n * NCLS + o] = (o < rng) ? val : -1e9f;
            }
        }
    }
}

extern "C" void kernel_launch(void* const* d_in, const int* in_sizes, int n_in,
                              void* d_out, int out_size, void* d_ws, size_t ws_size,
                              hipStream_t stream) {
    const float* et = (const float*)d_in[0];
    const int*   vb = (const int*)d_in[1];
    const float* aw = (const float*)d_in[2];
    const int*   vt = (const int*)d_in[3];
    const float* z0 = (const float*)d_in[4];
    const float* vf = (const float*)d_in[5];
    const float* Wp = (const float*)d_in[6];
    const float* bp = (const float*)d_in[7];
    const float* fg = (const float*)d_in[8];
    const float* fb = (const float*)d_in[9];
    float* out = (float*)d_out;

    char* ws = (char*)d_ws;
    unsigned short* projb = (unsigned short*)ws;              // 131072 B
    float* b1e           = (float*)(ws + 131072);             // 3072 B (+pad)
    unsigned short* W1e  = (unsigned short*)(ws + 134144);    // 393216 B
    unsigned short* W2b  = (unsigned short*)(ws + 527360);    // 393216 B
    unsigned short* Whb  = (unsigned short*)(ws + 920576);    // 24576 B
    float* swh           = (float*)(ws + 945152);             // 192 B (+pad)
    float2* zstat        = (float2*)(ws + 945408);            // 240128 B
    unsigned short* zhat = (unsigned short*)(ws + 1185536);   // 469*64*512 B -> ~16.6 MB

    WP wps[3];
    for (int h = 0; h < 3; ++h) {
        wps[h].W1 = (const float*)d_in[12 + 8 * h];
        wps[h].ng = (const float*)d_in[10 + 8 * h];
        wps[h].nb = (const float*)d_in[11 + 8 * h];
        wps[h].b1 = (const float*)d_in[13 + 8 * h];
        wps[h].W2 = (const float*)d_in[14 + 8 * h];
        wps[h].Wh = (const float*)d_in[16 + 8 * h];
        wps[h].W1e = W1e + h * 65536;
        wps[h].W2b = W2b + h * 65536;
        wps[h].Whb = Whb + h * 4096;
        wps[h].b1e = b1e + h * 256;
        wps[h].swh = swh + h * 16;
        wps[h].nc  = (h == 1) ? NCLS : 1;
    }
    k_prep<<<dim3(256, 5), 256, 0, stream>>>(et, Wp, bp, projb, vf, vt, out,
                                             wps[0], wps[1], wps[2]);

    k_zout<<<3750, 256, 0, stream>>>(projb, vb, aw, z0, fg, fb, out, zhat, zstat);

    HeadP hps[3];
    for (int h = 0; h < 3; ++h) {
        hps[h].W1e = W1e + h * 65536;
        hps[h].W2b = W2b + h * 65536;
        hps[h].Whb = Whb + h * 4096;
        hps[h].b1e = b1e + h * 256;
        hps[h].b2  = (const float*)d_in[15 + 8 * h];
        hps[h].bh  = (const float*)d_in[17 + 8 * h];
        hps[h].swh = swh + h * 16;
        hps[h].nc  = (h == 1) ? NCLS : 1;
    }
    k_heads<<<3 * NT, 512, 0, stream>>>(zhat, zstat, out + ORG,
                                        hps[0], hps[1], hps[2],
                                        out + OPB, out + OLG, out + OPL);
}

// Round 9
// 244.759 us; speedup vs baseline: 1.9029x; 1.0222x over previous
//
#include <hip/hip_runtime.h>
#include <math.h>

#define NV   30000
#define DD   256
#define KK   32
#define NCLS 11
#define NT   469   // row tiles of 64

// output layout (floats)
#define OZ  0
#define OPB 7680000
#define OLG 7710000
#define OPL 8040000
#define OMB 8070000
#define OMS 8100000
#define OML 8130000
#define OOF 8160000
#define ORG 8190000

typedef __bf16 bf16x8 __attribute__((ext_vector_type(8)));
typedef float  f32x4  __attribute__((ext_vector_type(4)));

__device__ __forceinline__ unsigned short f2b(float f) {
    unsigned u = __float_as_uint(f);
    u += 0x7fffu + ((u >> 16) & 1u);
    return (unsigned short)(u >> 16);
}

// tanh-form gelu: x * sigmoid(x*(c0 + c1*x^2)); |err| ~3e-4 << bf16 quantization
__device__ __forceinline__ float gelu_f(float x) {
    float x2 = x * x;
    float m = x * __builtin_fmaf(-0.0713548163f, x2, -1.5957691216f);
    float e = __expf(m);
    return x * __builtin_amdgcn_rcpf(1.0f + e);
}

__device__ __forceinline__ int swz(int row) { return (row + (row >> 3)) & 7; }
__device__ __forceinline__ int lidx(int row, int col) {
    return row * 256 + ((((col) >> 3) ^ swz(row)) << 3) + (col & 7);
}
__device__ __forceinline__ int physchunk(int ck, int row) {
    return (ck & ~7) | ((ck & 7) ^ swz(row));
}

// ------ merged prep: y==0 projT(bf16,transposed), y=1..3 weight prep, y==4 masks ------
struct WP {
    const float *W1, *ng, *nb, *b1, *W2, *Wh;
    unsigned short *W1e, *W2b, *Whb;
    float *b1e, *swh;
    int nc;
};

__global__ void k_prep(const float* __restrict__ et, const float* __restrict__ Wp,
                       const float* __restrict__ bp, unsigned short* __restrict__ projT,
                       const float* __restrict__ vf, const int* __restrict__ vt,
                       float* __restrict__ out,
                       WP wa, WP wb, WP wc) {
    __shared__ float es[DD];
    __shared__ float red[4], red2[4];
    if (blockIdx.y == 0) {
        int r = blockIdx.x, c = threadIdx.x;
        es[c] = et[r * DD + c];
        __syncthreads();
        const float4* w4 = (const float4*)(Wp + c * DD);
        float acc = bp[c];
#pragma unroll 16
        for (int d = 0; d < DD / 4; ++d) {
            float4 w = w4[d];
            acc += es[4 * d] * w.x + es[4 * d + 1] * w.y + es[4 * d + 2] * w.z + es[4 * d + 3] * w.w;
        }
        projT[c * DD + r] = f2b(acc);   // transposed: [d][token]
        return;
    }
    if (blockIdx.y == 4) {
        int n = blockIdx.x * 256 + threadIdx.x;
        if (n < NV) {
            float lb = vf[n * 23 + 21], ub = vf[n * 23 + 22];
            int t = vt[n];
            bool is_int = (t == 2);
            bool finite = (fabsf(lb) < 1e18f) && (fabsf(ub) < 1e18f);
            bool small_ = is_int && finite && (ub - lb <= 10.0f);
            float off = floorf(lb);
            float rngf = ceilf(ub) - off + 1.0f;
            rngf = fminf(fmaxf(rngf, 1.0f), (float)NCLS);
            out[OMB + n] = (t == 1) ? 1.0f : 0.0f;
            out[OMS + n] = small_ ? 1.0f : 0.0f;
            out[OML + n] = (is_int && !small_) ? 1.0f : 0.0f;
            out[OOF + n] = off;
            out[ORG + n] = (float)((int)rngf);
        }
        return;
    }
    WP wp = (blockIdx.y == 1) ? wa : ((blockIdx.y == 2) ? wb : wc);
    int j = blockIdx.x, d = threadIdx.x;
    float v1 = wp.W1[j * DD + d];
    wp.W1e[j * DD + d] = f2b(v1 * wp.ng[d]);
    wp.W2b[j * DD + d] = f2b(wp.W2[j * DD + d]);
    float p2 = 0.f;
    if (j < 16) {
        p2 = (j < wp.nc) ? wp.Wh[j * DD + d] : 0.f;
        wp.Whb[j * DD + d] = f2b(p2);
    }
    float p = v1 * wp.nb[d];
#pragma unroll
    for (int m = 1; m < 64; m <<= 1) { p += __shfl_xor(p, m); p2 += __shfl_xor(p2, m); }
    if ((d & 63) == 0) { red[d >> 6] = p; red2[d >> 6] = p2; }
    __syncthreads();
    if (d == 0) {
        wp.b1e[j] = wp.b1[j] + red[0] + red[1] + red[2] + red[3];
        if (j < 16) wp.swh[j] = red2[0] + red2[1] + red2[2] + red2[3];
    }
}

// ---- MFMA k_zout: z_des = awScatter @ projT^T; LN x2; zhat tile; zwh fold ----
__global__ __launch_bounds__(512)
void k_zout(const unsigned short* __restrict__ projT, const int* __restrict__ vb,
            const float* __restrict__ aw, const float* __restrict__ z0,
            const float* __restrict__ g, const float* __restrict__ b,
            const unsigned short* __restrict__ Whb, const float* __restrict__ swh,
            float* __restrict__ out, unsigned short* __restrict__ zhat,
            float* __restrict__ zwhT) {
    __shared__ unsigned short Al[64 * 256];   // 32 KB: awScatter -> zhat
    __shared__ float sqs[64 * 8], sqq[64 * 8];
    __shared__ float mvm[64], mvr[64], sig[64];
    __shared__ float gs[DD], bs[DD];
    __shared__ float swhs[48];
    int tid = threadIdx.x;
    int lane = tid & 63, wv = tid >> 6;
    int l15 = lane & 15, lq = lane >> 4;
    int n0 = blockIdx.x * 64;

    if (tid < 256) gs[tid] = g[tid];
    else           bs[tid - 256] = b[tid - 256];
    if (tid < 48) swhs[tid] = swh[tid];
    {
        uint4 z4 = make_uint4(0, 0, 0, 0);
        uint4* dst = (uint4*)Al;
#pragma unroll
        for (int j = 0; j < 4; ++j) dst[tid + j * 512] = z4;
    }
    __syncthreads();
    // scatter aw (bf16) into Al at col vb*32
    {
        int r = tid >> 3, sub = tid & 7;
        int n = n0 + r;
        if (n < NV) {
            int bb = vb[n];
            float4 a4 = *(const float4*)(aw + (size_t)n * KK + sub * 4);
            int j0 = bb * 32 + sub * 4;
            int phys = r * 256 + (physchunk(j0 >> 3, r) << 3) + (j0 & 7);
            ushort4 u;
            u.x = f2b(a4.x); u.y = f2b(a4.y); u.z = f2b(a4.z); u.w = f2b(a4.w);
            *(ushort4*)(Al + phys) = u;
        }
    }
    __syncthreads();

    int nb0 = wv * 32;   // this wave's 32 d-columns
    f32x4 acc[4][2];
#pragma unroll
    for (int mt = 0; mt < 4; ++mt)
#pragma unroll
        for (int nt = 0; nt < 2; ++nt) acc[mt][nt] = f32x4{0.f, 0.f, 0.f, 0.f};

    // GEMM: D[row][d] ; a = Al rows (m=row), b = projT rows (n=d)
    {
        const unsigned short* Bb = projT + (size_t)(nb0 + l15) * DD + lq * 8;
        bf16x8 bfr[2][2], afr[4];
#pragma unroll
        for (int nt = 0; nt < 2; ++nt) bfr[0][nt] = *(const bf16x8*)(Bb + nt * 16 * DD);
#pragma unroll
        for (int ks = 0; ks < 8; ++ks) {
            int cur = ks & 1;
            if (ks < 7) {
#pragma unroll
                for (int nt = 0; nt < 2; ++nt)
                    bfr[cur ^ 1][nt] = *(const bf16x8*)(Bb + nt * 16 * DD + (ks + 1) * 32);
            }
            int ck = ks * 4 + lq;
#pragma unroll
            for (int mt = 0; mt < 4; ++mt) {
                int row = mt * 16 + l15;
                afr[mt] = *(const bf16x8*)(Al + row * 256 + (physchunk(ck, row) << 3));
            }
#pragma unroll
            for (int nt = 0; nt < 2; ++nt)
#pragma unroll
                for (int mt = 0; mt < 4; ++mt)
                    acc[mt][nt] = __builtin_amdgcn_mfma_f32_16x16x32_bf16(afr[mt], bfr[cur][nt], acc[mt][nt], 0, 0, 0);
        }
    }
    // add z0 (coalesced), LN1 partials
#pragma unroll
    for (int mt = 0; mt < 4; ++mt)
#pragma unroll
        for (int nt = 0; nt < 2; ++nt) {
            int col = nb0 + nt * 16 + l15;
#pragma unroll
            for (int r = 0; r < 4; ++r) {
                int n = n0 + mt * 16 + lq * 4 + r;
                float zv = (n < NV) ? z0[(size_t)n * DD + col] : 0.f;
                acc[mt][nt][r] += zv;
            }
        }
#pragma unroll
    for (int mt = 0; mt < 4; ++mt)
#pragma unroll
        for (int r = 0; r < 4; ++r) {
            float s = acc[mt][0][r] + acc[mt][1][r];
            float q = acc[mt][0][r] * acc[mt][0][r] + acc[mt][1][r] * acc[mt][1][r];
#pragma unroll
            for (int m = 1; m < 16; m <<= 1) { s += __shfl_xor(s, m); q += __shfl_xor(q, m); }
            if (l15 == 0) { int row = mt * 16 + lq * 4 + r; sqs[row * 8 + wv] = s; sqq[row * 8 + wv] = q; }
        }
    __syncthreads();
    if (tid < 64) {
        float s = 0.f, q = 0.f;
#pragma unroll
        for (int w = 0; w < 8; ++w) { s += sqs[tid * 8 + w]; q += sqq[tid * 8 + w]; }
        float mean = s * (1.f / DD);
        float var  = q * (1.f / DD) - mean * mean;
        mvm[tid] = mean; mvr[tid] = rsqrtf(var + 1e-5f);
    }
    __syncthreads();
    // z, write zout, LN2 partials
    float zb[4][2][4];
#pragma unroll
    for (int mt = 0; mt < 4; ++mt)
#pragma unroll
        for (int nt = 0; nt < 2; ++nt) {
            int col = nb0 + nt * 16 + l15;
#pragma unroll
            for (int r = 0; r < 4; ++r) {
                int row = mt * 16 + lq * 4 + r;
                float z = (acc[mt][nt][r] - mvm[row]) * mvr[row] * gs[col] + bs[col];
                zb[mt][nt][r] = z;
                int n = n0 + row;
                if (n < NV) out[OZ + (size_t)n * DD + col] = z;
            }
        }
#pragma unroll
    for (int mt = 0; mt < 4; ++mt)
#pragma unroll
        for (int r = 0; r < 4; ++r) {
            float s = zb[mt][0][r] + zb[mt][1][r];
            float q = zb[mt][0][r] * zb[mt][0][r] + zb[mt][1][r] * zb[mt][1][r];
#pragma unroll
            for (int m = 1; m < 16; m <<= 1) { s += __shfl_xor(s, m); q += __shfl_xor(q, m); }
            if (l15 == 0) { int row = mt * 16 + lq * 4 + r; sqs[row * 8 + wv] = s; sqq[row * 8 + wv] = q; }
        }
    __syncthreads();
    if (tid < 64) {
        float s = 0.f, q = 0.f;
#pragma unroll
        for (int w = 0; w < 8; ++w) { s += sqs[tid * 8 + w]; q += sqq[tid * 8 + w]; }
        float m2 = s * (1.f / DD);
        float v2 = q * (1.f / DD) - m2 * m2;
        float r2 = rsqrtf(v2 + 1e-5f);
        mvm[tid] = m2; mvr[tid] = r2; sig[tid] = (v2 + 1e-5f) * r2;
    }
    __syncthreads();
    // zhat (bf16) into Al (overwrite aw scatter)
#pragma unroll
    for (int mt = 0; mt < 4; ++mt)
#pragma unroll
        for (int nt = 0; nt < 2; ++nt) {
            int col = nb0 + nt * 16 + l15;
#pragma unroll
            for (int r = 0; r < 4; ++r) {
                int row = mt * 16 + lq * 4 + r;
                Al[lidx(row, col)] = f2b((zb[mt][nt][r] - mvm[row]) * mvr[row]);
            }
        }
    __syncthreads();
    // zwh GEMM on waves 0..3: D[o(48)][n(16 per wave)]
    if (wv < 4) {
        f32x4 ac2[3];
#pragma unroll
        for (int mf = 0; mf < 3; ++mf) ac2[mf] = f32x4{0.f, 0.f, 0.f, 0.f};
        const unsigned short* Ab = Whb + (size_t)l15 * DD + lq * 8;
        int rowb = wv * 16 + l15;
#pragma unroll
        for (int ks = 0; ks < 8; ++ks) {
            int ck = ks * 4 + lq;
            bf16x8 bb2 = *(const bf16x8*)(Al + rowb * 256 + (physchunk(ck, rowb) << 3));
#pragma unroll
            for (int mf = 0; mf < 3; ++mf) {
                bf16x8 aa2 = *(const bf16x8*)(Ab + (size_t)mf * 16 * DD + ks * 32);
                ac2[mf] = __builtin_amdgcn_mfma_f32_16x16x32_bf16(aa2, bb2, ac2[mf], 0, 0, 0);
            }
        }
        int nl = wv * 16 + l15;
        float sg = sig[nl], mu = mvm[nl];
#pragma unroll
        for (int mf = 0; mf < 3; ++mf)
#pragma unroll
            for (int r = 0; r < 4; ++r) {
                int o = mf * 16 + lq * 4 + r;
                zwhT[(size_t)blockIdx.x * 3072 + o * 64 + nl] = sg * ac2[mf][r] + mu * swhs[o];
            }
    }
    // copy zhat tile out (pre-swizzled)
    {
        uint4* dstg = (uint4*)(zhat + (size_t)n0 * 256);
        const uint4* srcl = (const uint4*)Al;
#pragma unroll
        for (int j = 0; j < 4; ++j) dstg[tid + j * 512] = srcl[tid + j * 512];
    }
}

// ---------------- per-head MLP kernel: transposed GEMMs ----------------
struct HeadP {
    const unsigned short *W1e, *W2b, *Whb;
    const float *b1e, *b2, *bh;
    int nc;
};

__global__ __launch_bounds__(512, 4)
void k_heads(const unsigned short* __restrict__ zhat, const float* __restrict__ zwhT,
             const float* __restrict__ ranges,
             HeadP h0, HeadP h1p, HeadP h2p,
             float* __restrict__ opb, float* __restrict__ olg, float* __restrict__ opl) {
    __shared__ unsigned short hl1[64 * 256];  // zhat -> h
    __shared__ unsigned short hl2[64 * 256];  // h1 -> f32 partials
    __shared__ float b1s[DD], b2s[DD];
    __shared__ float zws[16 * 64];
    __shared__ float rgs[64];
    __shared__ float bhs[16];

    int head = blockIdx.x / NT;
    int tile = blockIdx.x % NT;
    HeadP hp = (head == 0) ? h0 : ((head == 1) ? h1p : h2p);
    int nc = hp.nc;
    int n0 = tile * 64;
    int tid = threadIdx.x, lane = tid & 63, wv = tid >> 6;
    int l15 = lane & 15, lq = lane >> 4;
    int M0 = wv * 32;   // this wave's 32 feature rows

    {
        const uint4* src = (const uint4*)(zhat + (size_t)n0 * 256);
        uint4* dst = (uint4*)hl1;
#pragma unroll
        for (int j = 0; j < 4; ++j) dst[tid + j * 512] = src[tid + j * 512];
    }
    if (tid < 256) b1s[tid] = hp.b1e[tid];
    else           b2s[tid - 256] = hp.b2[tid - 256];
    ((float2*)zws)[tid] = ((const float2*)(zwhT + (size_t)(tile * 3 + head) * 1024))[tid];
    if (tid < 64) { int n = n0 + tid; rgs[tid] = (n < NV) ? ranges[n] : 0.f; }
    else if (tid < 80) { int o = tid - 64; bhs[o] = (o < nc) ? hp.bh[o] : 0.f; }
    __syncthreads();

    f32x4 acc[2][4];
#pragma unroll
    for (int mt = 0; mt < 2; ++mt)
#pragma unroll
        for (int nt = 0; nt < 4; ++nt) acc[mt][nt] = f32x4{0.f, 0.f, 0.f, 0.f};

    // ---- GEMM1-T: D1[j][n], a = W1e rows (global, ring), b = zhat rows (LDS) ----
    {
        const unsigned short* Ab = hp.W1e + (size_t)(M0 + l15) * DD + lq * 8;
        bf16x8 afr[2][2], bfr[4];
#pragma unroll
        for (int mt = 0; mt < 2; ++mt) afr[0][mt] = *(const bf16x8*)(Ab + mt * 16 * DD);
#pragma unroll
        for (int ks = 0; ks < 8; ++ks) {
            int cur = ks & 1;
            if (ks < 7) {
#pragma unroll
                for (int mt = 0; mt < 2; ++mt)
                    afr[cur ^ 1][mt] = *(const bf16x8*)(Ab + mt * 16 * DD + (ks + 1) * 32);
            }
            int ck = ks * 4 + lq;
#pragma unroll
            for (int nt = 0; nt < 4; ++nt) {
                int row = nt * 16 + l15;
                bfr[nt] = *(const bf16x8*)(hl1 + row * 256 + (physchunk(ck, row) << 3));
            }
#pragma unroll
            for (int nt = 0; nt < 4; ++nt)
#pragma unroll
                for (int mt = 0; mt < 2; ++mt)
                    acc[mt][nt] = __builtin_amdgcn_mfma_f32_16x16x32_bf16(afr[cur][mt], bfr[nt], acc[mt][nt], 0, 0, 0);
        }
    }
    // epilogue 1 -> hl2 (b64 vector writes; no barrier needed: different buffer)
#pragma unroll
    for (int mt = 0; mt < 2; ++mt) {
        int jb = M0 + mt * 16 + lq * 4;
        float4 bias = *(const float4*)(b1s + jb);
        int chunk = jb >> 3;
#pragma unroll
        for (int nt = 0; nt < 4; ++nt) {
            int n = nt * 16 + l15;
            ushort4 u;
            u.x = f2b(gelu_f(acc[mt][nt][0] + bias.x));
            u.y = f2b(gelu_f(acc[mt][nt][1] + bias.y));
            u.z = f2b(gelu_f(acc[mt][nt][2] + bias.z));
            u.w = f2b(gelu_f(acc[mt][nt][3] + bias.w));
            *(ushort4*)(hl2 + n * 256 + (physchunk(chunk, n) << 3) + (jb & 7)) = u;
        }
    }
    __syncthreads();

    // ---- GEMM2-T: a = W2b rows, b = h1 rows (hl2) ----
#pragma unroll
    for (int mt = 0; mt < 2; ++mt)
#pragma unroll
        for (int nt = 0; nt < 4; ++nt) acc[mt][nt] = f32x4{0.f, 0.f, 0.f, 0.f};
    {
        const unsigned short* Ab = hp.W2b + (size_t)(M0 + l15) * DD + lq * 8;
        bf16x8 afr[2][2], bfr[4];
#pragma unroll
        for (int mt = 0; mt < 2; ++mt) afr[0][mt] = *(const bf16x8*)(Ab + mt * 16 * DD);
#pragma unroll
        for (int ks = 0; ks < 8; ++ks) {
            int cur = ks & 1;
            if (ks < 7) {
#pragma unroll
                for (int mt = 0; mt < 2; ++mt)
                    afr[cur ^ 1][mt] = *(const bf16x8*)(Ab + mt * 16 * DD + (ks + 1) * 32);
            }
            int ck = ks * 4 + lq;
#pragma unroll
            for (int nt = 0; nt < 4; ++nt) {
                int row = nt * 16 + l15;
                bfr[nt] = *(const bf16x8*)(hl2 + row * 256 + (physchunk(ck, row) << 3));
            }
#pragma unroll
            for (int nt = 0; nt < 4; ++nt)
#pragma unroll
                for (int mt = 0; mt < 2; ++mt)
                    acc[mt][nt] = __builtin_amdgcn_mfma_f32_16x16x32_bf16(afr[cur][mt], bfr[nt], acc[mt][nt], 0, 0, 0);
        }
    }
    // epilogue 2: gelu -> h into hl1 (zhat dead after GEMM1+barrier)
#pragma unroll
    for (int mt = 0; mt < 2; ++mt) {
        int jb = M0 + mt * 16 + lq * 4;
        float4 bias = *(const float4*)(b2s + jb);
        int chunk = jb >> 3;
#pragma unroll
        for (int nt = 0; nt < 4; ++nt) {
            int n = nt * 16 + l15;
            ushort4 u;
            u.x = f2b(gelu_f(acc[mt][nt][0] + bias.x));
            u.y = f2b(gelu_f(acc[mt][nt][1] + bias.y));
            u.z = f2b(gelu_f(acc[mt][nt][2] + bias.z));
            u.w = f2b(gelu_f(acc[mt][nt][3] + bias.w));
            *(ushort4*)(hl1 + n * 256 + (physchunk(chunk, n) << 3) + (jb & 7)) = u;
        }
    }
    __syncthreads();

    // ---- projection: split-k, wave wv handles k-slice [wv*32, wv*32+32) ----
    f32x4 ap[4];
#pragma unroll
    for (int nt = 0; nt < 4; ++nt) ap[nt] = f32x4{0.f, 0.f, 0.f, 0.f};
    {
        bf16x8 afr = *(const bf16x8*)(hp.Whb + (size_t)l15 * DD + wv * 32 + lq * 8);
        int ck = wv * 4 + lq;
#pragma unroll
        for (int nt = 0; nt < 4; ++nt) {
            int row = nt * 16 + l15;
            bf16x8 bfr = *(const bf16x8*)(hl1 + row * 256 + (physchunk(ck, row) << 3));
            ap[nt] = __builtin_amdgcn_mfma_f32_16x16x32_bf16(afr, bfr, ap[nt], 0, 0, 0);
        }
    }
    // partials into hl2 (f32): hl2 last read was GEMM2, barrier passed
    {
        float* pb = (float*)hl2;
#pragma unroll
        for (int nt = 0; nt < 4; ++nt)
#pragma unroll
            for (int r = 0; r < 4; ++r)
                pb[wv * 1024 + (lq * 4 + r) * 64 + nt * 16 + l15] = ap[nt][r];
    }
    __syncthreads();

    // combine + store
    const float* pb = (const float*)hl2;
    for (int idx = tid; idx < 64 * nc; idx += 512) {
        int o = idx >> 6, n = idx & 63;
        float val = bhs[o] + zws[o * 64 + n];
#pragma unroll
        for (int w = 0; w < 8; ++w) val += pb[w * 1024 + o * 64 + n];
        int ng = n0 + n;
        if (ng < NV) {
            if (head == 0)      opb[ng] = __builtin_amdgcn_rcpf(1.f + __expf(-val));
            else if (head == 2) opl[ng] = val;
            else {
                int rng = (int)rgs[n];
                olg[(size_t)ng * NCLS + o] = (o < rng) ? val : -1e9f;
            }
        }
    }
}

extern "C" void kernel_launch(void* const* d_in, const int* in_sizes, int n_in,
                              void* d_out, int out_size, void* d_ws, size_t ws_size,
                              hipStream_t stream) {
    const float* et = (const float*)d_in[0];
    const int*   vb = (const int*)d_in[1];
    const float* aw = (const float*)d_in[2];
    const int*   vt = (const int*)d_in[3];
    const float* z0 = (const float*)d_in[4];
    const float* vf = (const float*)d_in[5];
    const float* Wp = (const float*)d_in[6];
    const float* bp = (const float*)d_in[7];
    const float* fg = (const float*)d_in[8];
    const float* fb = (const float*)d_in[9];
    float* out = (float*)d_out;

    char* ws = (char*)d_ws;
    unsigned short* projT = (unsigned short*)ws;              // 131072 B
    float* b1e           = (float*)(ws + 131072);             // 3072 (+pad)
    unsigned short* W1e  = (unsigned short*)(ws + 134144);    // 393216
    unsigned short* W2b  = (unsigned short*)(ws + 527360);    // 393216
    unsigned short* Whb  = (unsigned short*)(ws + 920576);    // 24576 (48 rows x 256)
    float* swh           = (float*)(ws + 945152);             // 192 (+pad)
    float* zwhT          = (float*)(ws + 945408);             // 469*3072*4 = 5763072
    unsigned short* zhat = (unsigned short*)(ws + 6708480);   // 469*64*512 = 15368192 -> ~22.1 MB

    WP wps[3];
    for (int h = 0; h < 3; ++h) {
        wps[h].W1 = (const float*)d_in[12 + 8 * h];
        wps[h].ng = (const float*)d_in[10 + 8 * h];
        wps[h].nb = (const float*)d_in[11 + 8 * h];
        wps[h].b1 = (const float*)d_in[13 + 8 * h];
        wps[h].W2 = (const float*)d_in[14 + 8 * h];
        wps[h].Wh = (const float*)d_in[16 + 8 * h];
        wps[h].W1e = W1e + h * 65536;
        wps[h].W2b = W2b + h * 65536;
        wps[h].Whb = Whb + h * 4096;
        wps[h].b1e = b1e + h * 256;
        wps[h].swh = swh + h * 16;
        wps[h].nc  = (h == 1) ? NCLS : 1;
    }
    k_prep<<<dim3(256, 5), 256, 0, stream>>>(et, Wp, bp, projT, vf, vt, out,
                                             wps[0], wps[1], wps[2]);

    k_zout<<<NT, 512, 0, stream>>>(projT, vb, aw, z0, fg, fb, Whb, swh,
                                   out, zhat, zwhT);

    HeadP hps[3];
    for (int h = 0; h < 3; ++h) {
        hps[h].W1e = W1e + h * 65536;
        hps[h].W2b = W2b + h * 65536;
        hps[h].Whb = Whb + h * 4096;
        hps[h].b1e = b1e + h * 256;
        hps[h].b2  = (const float*)d_in[15 + 8 * h];
        hps[h].bh  = (const float*)d_in[17 + 8 * h];
        hps[h].nc  = (h == 1) ? NCLS : 1;
    }
    k_heads<<<3 * NT, 512, 0, stream>>>(zhat, zwhT, out + ORG,
                                        hps[0], hps[1], hps[2],
                                        out + OPB, out + OLG, out + OPL);
}